// Round 1
// baseline (6237.246 us; speedup 1.0000x reference)
//
#include <hip/hip_runtime.h>
#include <math.h>

#define NN 100000
#define NE 1600000
#define EPSF 1e-5f

// ---------------- degree / norm ----------------
__global__ void k_init_deg(float* deg) {
    int i = blockIdx.x * 256 + threadIdx.x;
    if (i < NN) deg[i] = 1.0f;  // self-loop
}

__global__ void k_deg_accum(const int* __restrict__ dst, float* deg) {
    int e = blockIdx.x * 256 + threadIdx.x;
    if (e < NE) atomicAdd(&deg[dst[e]], 1.0f);
}

__global__ void k_dinv(float* deg) {
    int i = blockIdx.x * 256 + threadIdx.x;
    if (i < NN) deg[i] = rsqrtf(deg[i]);
}

// ---------------- GEMM: [n,128] @ [128,128] -> [n,128] ----------------
// 64x64 output tile per block, 256 threads, 4x4 micro-tile.
__global__ __launch_bounds__(256) void k_gemm128(const float* __restrict__ X,
                                                 const float* __restrict__ W,
                                                 float* __restrict__ Y, int n) {
    __shared__ float Xl[64 * 128];   // 32 KB
    __shared__ float Wl[128 * 64];   // 32 KB
    int t = threadIdx.x;
    int row0 = blockIdx.x * 64;
    int col0 = blockIdx.y * 64;

#pragma unroll
    for (int i = 0; i < 8; i++) {
        int idx = t + i * 256;       // 2048 float4 units
        int r = idx >> 5;
        int kq = idx & 31;
        int gr = row0 + r;
        float4 v = make_float4(0.f, 0.f, 0.f, 0.f);
        if (gr < n) v = reinterpret_cast<const float4*>(X + (size_t)gr * 128)[kq];
        reinterpret_cast<float4*>(Xl + r * 128)[kq] = v;
    }
#pragma unroll
    for (int i = 0; i < 8; i++) {
        int idx = t + i * 256;
        int k = idx >> 4;
        int cq = idx & 15;
        reinterpret_cast<float4*>(Wl + k * 64)[cq] =
            reinterpret_cast<const float4*>(W + k * 128 + col0)[cq];
    }
    __syncthreads();

    int tx = t & 15, ty = t >> 4;
    int rb = ty * 4, cb = tx * 4;
    float acc[4][4] = {};
    for (int k = 0; k < 128; k += 4) {
        float4 xv[4], wv[4];
#pragma unroll
        for (int i = 0; i < 4; i++)
            xv[i] = *reinterpret_cast<const float4*>(Xl + (rb + i) * 128 + k);
#pragma unroll
        for (int j = 0; j < 4; j++)
            wv[j] = *reinterpret_cast<const float4*>(Wl + (k + j) * 64 + cb);
#pragma unroll
        for (int i = 0; i < 4; i++) {
            acc[i][0] += xv[i].x * wv[0].x + xv[i].y * wv[1].x + xv[i].z * wv[2].x + xv[i].w * wv[3].x;
            acc[i][1] += xv[i].x * wv[0].y + xv[i].y * wv[1].y + xv[i].z * wv[2].y + xv[i].w * wv[3].y;
            acc[i][2] += xv[i].x * wv[0].z + xv[i].y * wv[1].z + xv[i].z * wv[2].z + xv[i].w * wv[3].z;
            acc[i][3] += xv[i].x * wv[0].w + xv[i].y * wv[1].w + xv[i].z * wv[2].w + xv[i].w * wv[3].w;
        }
    }
#pragma unroll
    for (int i = 0; i < 4; i++) {
        int gr = row0 + rb + i;
        if (gr < n) {
            float4 o = make_float4(acc[i][0], acc[i][1], acc[i][2], acc[i][3]);
            *reinterpret_cast<float4*>(Y + (size_t)gr * 128 + col0 + cb) = o;
        }
    }
}

// ---------------- GEMM: [n,128] @ [128,40] -> [n,40] ----------------
__global__ __launch_bounds__(256) void k_gemm40(const float* __restrict__ X,
                                                const float* __restrict__ W,
                                                float* __restrict__ Y, int n) {
    __shared__ float Wt[40 * 132];  // transposed [c][k], padded stride 132
    int t = threadIdx.x;
    for (int idx = t; idx < 40 * 128; idx += 256) {
        int c = idx >> 7, k = idx & 127;
        Wt[c * 132 + k] = W[k * 40 + c];
    }
    __syncthreads();
    int gt = blockIdx.x * 256 + t;
    if (gt >= n * 40) return;
    int row = gt / 40;
    int c = gt - row * 40;
    const float4* xr = reinterpret_cast<const float4*>(X + (size_t)row * 128);
    const float4* wr = reinterpret_cast<const float4*>(Wt + c * 132);
    float acc = 0.f;
#pragma unroll
    for (int kq = 0; kq < 32; kq++) {
        float4 a = xr[kq];
        float4 b = wr[kq];
        acc += a.x * b.x + a.y * b.y + a.z * b.z + a.w * b.w;
    }
    Y[gt] = acc;
}

// ---------------- self-loop init: agg = dinv^2 * xw ----------------
__global__ void k_selfloop128(const float* __restrict__ xw, float* __restrict__ agg,
                              const float* __restrict__ dinv) {
    int gt = blockIdx.x * 256 + threadIdx.x;  // over NN*32 float4 units
    if (gt >= NN * 32) return;
    int i = gt >> 5;
    float di = dinv[i];
    float c = di * di;
    float4 v = reinterpret_cast<const float4*>(xw)[gt];
    float4 o = make_float4(c * v.x, c * v.y, c * v.z, c * v.w);
    reinterpret_cast<float4*>(agg)[gt] = o;
}

__global__ void k_selfloop40(const float* __restrict__ xw, float* __restrict__ agg,
                             const float* __restrict__ dinv) {
    int gt = blockIdx.x * 256 + threadIdx.x;  // over NN*40 scalars
    if (gt >= NN * 40) return;
    int i = gt / 40;
    float di = dinv[i];
    agg[gt] = di * di * xw[gt];
}

// ---------------- edge scatter (atomic) ----------------
__global__ void k_scatter128(const float* __restrict__ xw, float* __restrict__ agg,
                             const int* __restrict__ src, const int* __restrict__ dst,
                             const float* __restrict__ dinv) {
    int gt = blockIdx.x * 256 + threadIdx.x;  // NE*32 work items (float4 per edge)
    int e = gt >> 5;
    int fq = gt & 31;
    if (e >= NE) return;
    int s = src[e], d = dst[e];
    float coef = dinv[s] * dinv[d];
    float4 v = reinterpret_cast<const float4*>(xw + (size_t)s * 128)[fq];
    float* ap = agg + (size_t)d * 128 + fq * 4;
    atomicAdd(ap + 0, coef * v.x);
    atomicAdd(ap + 1, coef * v.y);
    atomicAdd(ap + 2, coef * v.z);
    atomicAdd(ap + 3, coef * v.w);
}

__global__ void k_scatter40(const float* __restrict__ xw, float* __restrict__ agg,
                            const int* __restrict__ src, const int* __restrict__ dst,
                            const float* __restrict__ dinv) {
    int gt = blockIdx.x * 256 + threadIdx.x;  // NE*40 work items
    if (gt >= NE * 40) return;
    int e = gt / 40;
    int f = gt - e * 40;
    int s = src[e], d = dst[e];
    float coef = dinv[s] * dinv[d];
    atomicAdd(&agg[(size_t)d * 40 + f], coef * xw[(size_t)s * 40 + f]);
}

// ---------------- batch norm ----------------
__global__ void k_zero_stats(float* stats) {
    stats[threadIdx.x] = 0.f;  // 256 threads
}

__global__ __launch_bounds__(128) void k_bn_stats(const float* __restrict__ h,
                                                  float* __restrict__ stats) {
    int f = threadIdx.x;  // 128 threads = feature
    float s = 0.f, s2 = 0.f;
    for (int r = blockIdx.x; r < NN; r += gridDim.x) {
        float v = h[(size_t)r * 128 + f];
        s += v;
        s2 += v * v;
    }
    atomicAdd(&stats[f], s);
    atomicAdd(&stats[128 + f], s2);
}

__global__ void k_bn_apply(float* __restrict__ h, const float* __restrict__ stats,
                           const float* __restrict__ g, const float* __restrict__ be) {
    int gt = blockIdx.x * 256 + threadIdx.x;  // NN*128 exact
    int f = gt & 127;
    float mu = stats[f] * (1.0f / NN);
    float var = stats[128 + f] * (1.0f / NN) - mu * mu;
    float sc = rsqrtf(var + EPSF) * g[f];
    float v = (h[gt] - mu) * sc + be[f];
    h[gt] = fmaxf(v, 0.0f);
}

// ---------------- bias + log_softmax ----------------
__global__ __launch_bounds__(256) void k_logsoftmax(const float* __restrict__ agg,
                                                    const float* __restrict__ b2,
                                                    float* __restrict__ out) {
    int row = blockIdx.x * 4 + (threadIdx.x >> 6);
    int lane = threadIdx.x & 63;
    if (row >= NN) return;
    float v = (lane < 40) ? agg[(size_t)row * 40 + lane] + b2[lane] : -1e30f;
    float m = v;
#pragma unroll
    for (int o = 32; o; o >>= 1) m = fmaxf(m, __shfl_xor(m, o));
    float ex = (lane < 40) ? expf(v - m) : 0.f;
    float sum = ex;
#pragma unroll
    for (int o = 32; o; o >>= 1) sum += __shfl_xor(sum, o);
    if (lane < 40) out[(size_t)row * 40 + lane] = v - m - logf(sum);
}

// ---------------- launcher ----------------
extern "C" void kernel_launch(void* const* d_in, const int* in_sizes, int n_in,
                              void* d_out, int out_size, void* d_ws, size_t ws_size,
                              hipStream_t stream) {
    const float* x  = (const float*)d_in[0];
    const int* ei   = (const int*)d_in[1];
    const int* src  = ei;
    const int* dst  = ei + NE;
    const float* W0 = (const float*)d_in[2];
    const float* g0 = (const float*)d_in[4];
    const float* be0= (const float*)d_in[5];
    const float* W1 = (const float*)d_in[6];
    const float* g1 = (const float*)d_in[8];
    const float* be1= (const float*)d_in[9];
    const float* W2 = (const float*)d_in[10];
    const float* b2 = (const float*)d_in[11];
    float* out = (float*)d_out;

    float* ws    = (float*)d_ws;
    float* dinv  = ws;                       // NN floats
    float* stats = ws + 100096;              // 256 floats
    float* bufA  = ws + 100352;              // NN*128
    float* bufB  = bufA + (size_t)NN * 128;  // NN*128

    // norm
    k_init_deg<<<(NN + 255) / 256, 256, 0, stream>>>(dinv);
    k_deg_accum<<<NE / 256, 256, 0, stream>>>(dst, dinv);
    k_dinv<<<(NN + 255) / 256, 256, 0, stream>>>(dinv);

    dim3 gg((NN + 63) / 64, 2);

    // ---- layer 0 ----
    k_gemm128<<<gg, 256, 0, stream>>>(x, W0, bufA, NN);
    k_selfloop128<<<(NN * 32 + 255) / 256, 256, 0, stream>>>(bufA, bufB, dinv);
    k_scatter128<<<NE * 32 / 256, 256, 0, stream>>>(bufA, bufB, src, dst, dinv);
    k_zero_stats<<<1, 256, 0, stream>>>(stats);
    k_bn_stats<<<1024, 128, 0, stream>>>(bufB, stats);
    k_bn_apply<<<NN * 128 / 256, 256, 0, stream>>>(bufB, stats, g0, be0);

    // ---- layer 1 ----
    k_gemm128<<<gg, 256, 0, stream>>>(bufB, W1, bufA, NN);
    k_selfloop128<<<(NN * 32 + 255) / 256, 256, 0, stream>>>(bufA, bufB, dinv);
    k_scatter128<<<NE * 32 / 256, 256, 0, stream>>>(bufA, bufB, src, dst, dinv);
    k_zero_stats<<<1, 256, 0, stream>>>(stats);
    k_bn_stats<<<1024, 128, 0, stream>>>(bufB, stats);
    k_bn_apply<<<NN * 128 / 256, 256, 0, stream>>>(bufB, stats, g1, be1);

    // ---- layer 2 ----
    k_gemm40<<<(NN * 40 + 255) / 256, 256, 0, stream>>>(bufB, W2, bufA, NN);
    k_selfloop40<<<(NN * 40 + 255) / 256, 256, 0, stream>>>(bufA, bufB, dinv);
    k_scatter40<<<NE * 40 / 256, 256, 0, stream>>>(bufA, bufB, src, dst, dinv);
    k_logsoftmax<<<(NN + 3) / 4, 256, 0, stream>>>(bufB, b2, out);
}

// Round 2
// 1141.499 us; speedup vs baseline: 5.4641x; 5.4641x over previous
//
#include <hip/hip_runtime.h>
#include <math.h>

#define NN 100000
#define NE 1600000
#define EPSF 1e-5f
#define SCAN_BLK 1024
#define NSCAN ((NN + SCAN_BLK - 1) / SCAN_BLK)   // 98

// ---------------- CSR build ----------------
__global__ void k_zero_ints(int* p, int n) {
    int i = blockIdx.x * 256 + threadIdx.x;
    if (i < n) p[i] = 0;
}

__global__ void k_count(const int* __restrict__ dst, int* __restrict__ ideg) {
    int e = blockIdx.x * 256 + threadIdx.x;
    if (e < NE) atomicAdd(&ideg[dst[e]], 1);
}

__global__ void k_dinv(const int* __restrict__ ideg, float* __restrict__ dinv) {
    int i = blockIdx.x * 256 + threadIdx.x;
    if (i < NN) dinv[i] = rsqrtf((float)(ideg[i] + 1));  // +1 self-loop
}

__global__ __launch_bounds__(SCAN_BLK) void k_scan1(const int* __restrict__ ideg,
                                                    int* __restrict__ rowstart,
                                                    int* __restrict__ bsum) {
    __shared__ int tmp[SCAN_BLK];
    int i = blockIdx.x * SCAN_BLK + threadIdx.x;
    int v = (i < NN) ? ideg[i] : 0;
    tmp[threadIdx.x] = v;
    __syncthreads();
    for (int o = 1; o < SCAN_BLK; o <<= 1) {
        int t = (threadIdx.x >= o) ? tmp[threadIdx.x - o] : 0;
        __syncthreads();
        tmp[threadIdx.x] += t;
        __syncthreads();
    }
    if (i < NN) rowstart[i] = tmp[threadIdx.x] - v;  // exclusive
    if (threadIdx.x == SCAN_BLK - 1) bsum[blockIdx.x] = tmp[SCAN_BLK - 1];
}

__global__ void k_scan2(int* bsum) {  // single thread, 98 elems: serialize
    if (threadIdx.x == 0 && blockIdx.x == 0) {
        int run = 0;
        for (int b = 0; b < NSCAN; b++) {
            int t = bsum[b];
            bsum[b] = run;
            run += t;
        }
    }
}

__global__ __launch_bounds__(SCAN_BLK) void k_scan3(int* __restrict__ rowstart,
                                                    const int* __restrict__ bsum) {
    int i = blockIdx.x * SCAN_BLK + threadIdx.x;
    if (i < NN) rowstart[i] += bsum[blockIdx.x];
    if (i == 0) rowstart[NN] = NE;
}

__global__ void k_copy_ints(const int* __restrict__ a, int* __restrict__ b) {
    int i = blockIdx.x * 256 + threadIdx.x;
    if (i < NN) b[i] = a[i];
}

__global__ void k_fill(const int* __restrict__ src, const int* __restrict__ dst,
                       int* __restrict__ cursor, int* __restrict__ csr) {
    int e = blockIdx.x * 256 + threadIdx.x;
    if (e >= NE) return;
    int p = atomicAdd(&cursor[dst[e]], 1);
    csr[p] = src[e];
}

// ---------------- GEMM: [n,128] @ [128,128] -> [n,128] ----------------
__global__ __launch_bounds__(256) void k_gemm128(const float* __restrict__ X,
                                                 const float* __restrict__ W,
                                                 float* __restrict__ Y, int n) {
    __shared__ float Xl[64 * 128];
    __shared__ float Wl[128 * 64];
    int t = threadIdx.x;
    int row0 = blockIdx.x * 64;
    int col0 = blockIdx.y * 64;

#pragma unroll
    for (int i = 0; i < 8; i++) {
        int idx = t + i * 256;
        int r = idx >> 5;
        int kq = idx & 31;
        int gr = row0 + r;
        float4 v = make_float4(0.f, 0.f, 0.f, 0.f);
        if (gr < n) v = reinterpret_cast<const float4*>(X + (size_t)gr * 128)[kq];
        reinterpret_cast<float4*>(Xl + r * 128)[kq] = v;
    }
#pragma unroll
    for (int i = 0; i < 8; i++) {
        int idx = t + i * 256;
        int k = idx >> 4;
        int cq = idx & 15;
        reinterpret_cast<float4*>(Wl + k * 64)[cq] =
            reinterpret_cast<const float4*>(W + k * 128 + col0)[cq];
    }
    __syncthreads();

    int tx = t & 15, ty = t >> 4;
    int rb = ty * 4, cb = tx * 4;
    float acc[4][4] = {};
    for (int k = 0; k < 128; k += 4) {
        float4 xv[4], wv[4];
#pragma unroll
        for (int i = 0; i < 4; i++)
            xv[i] = *reinterpret_cast<const float4*>(Xl + (rb + i) * 128 + k);
#pragma unroll
        for (int j = 0; j < 4; j++)
            wv[j] = *reinterpret_cast<const float4*>(Wl + (k + j) * 64 + cb);
#pragma unroll
        for (int i = 0; i < 4; i++) {
            acc[i][0] += xv[i].x * wv[0].x + xv[i].y * wv[1].x + xv[i].z * wv[2].x + xv[i].w * wv[3].x;
            acc[i][1] += xv[i].x * wv[0].y + xv[i].y * wv[1].y + xv[i].z * wv[2].y + xv[i].w * wv[3].y;
            acc[i][2] += xv[i].x * wv[0].z + xv[i].y * wv[1].z + xv[i].z * wv[2].z + xv[i].w * wv[3].z;
            acc[i][3] += xv[i].x * wv[0].w + xv[i].y * wv[1].w + xv[i].z * wv[2].w + xv[i].w * wv[3].w;
        }
    }
#pragma unroll
    for (int i = 0; i < 4; i++) {
        int gr = row0 + rb + i;
        if (gr < n) {
            float4 o = make_float4(acc[i][0], acc[i][1], acc[i][2], acc[i][3]);
            *reinterpret_cast<float4*>(Y + (size_t)gr * 128 + col0 + cb) = o;
        }
    }
}

// ---------------- GEMM: [n,128] @ [128,40] -> [n,40] ----------------
__global__ __launch_bounds__(256) void k_gemm40(const float* __restrict__ X,
                                                const float* __restrict__ W,
                                                float* __restrict__ Y, int n) {
    __shared__ float Wt[40 * 132];
    int t = threadIdx.x;
    for (int idx = t; idx < 40 * 128; idx += 256) {
        int c = idx >> 7, k = idx & 127;
        Wt[c * 132 + k] = W[k * 40 + c];
    }
    __syncthreads();
    int gt = blockIdx.x * 256 + t;
    if (gt >= n * 40) return;
    int row = gt / 40;
    int c = gt - row * 40;
    const float4* xr = reinterpret_cast<const float4*>(X + (size_t)row * 128);
    const float4* wr = reinterpret_cast<const float4*>(Wt + c * 132);
    float acc = 0.f;
#pragma unroll
    for (int kq = 0; kq < 32; kq++) {
        float4 a = xr[kq];
        float4 b = wr[kq];
        acc += a.x * b.x + a.y * b.y + a.z * b.z + a.w * b.w;
    }
    Y[gt] = acc;
}

// ---------------- CSR gather, 128 features (self-loop fused) ----------------
__global__ __launch_bounds__(256) void k_gather128(const float* __restrict__ xw,
                                                   float* __restrict__ agg,
                                                   const int* __restrict__ rowstart,
                                                   const int* __restrict__ csr,
                                                   const float* __restrict__ dinv) {
    int node = blockIdx.x * 4 + (threadIdx.x >> 6);
    if (node >= NN) return;
    int lane = threadIdx.x & 63;
    float dd = dinv[node];
    float2 self = reinterpret_cast<const float2*>(xw + (size_t)node * 128)[lane];
    float2 acc = make_float2(dd * dd * self.x, dd * dd * self.y);
    int p = rowstart[node], pe = rowstart[node + 1];
    for (; p + 2 <= pe; p += 2) {
        int sA = csr[p], sB = csr[p + 1];
        float cA = dd * dinv[sA], cB = dd * dinv[sB];
        float2 vA = reinterpret_cast<const float2*>(xw + (size_t)sA * 128)[lane];
        float2 vB = reinterpret_cast<const float2*>(xw + (size_t)sB * 128)[lane];
        acc.x += cA * vA.x + cB * vB.x;
        acc.y += cA * vA.y + cB * vB.y;
    }
    if (p < pe) {
        int s = csr[p];
        float c = dd * dinv[s];
        float2 v = reinterpret_cast<const float2*>(xw + (size_t)s * 128)[lane];
        acc.x += c * v.x;
        acc.y += c * v.y;
    }
    reinterpret_cast<float2*>(agg + (size_t)node * 128)[lane] = acc;
}

// ---------------- CSR gather 40 + bias + log_softmax (fused) ----------------
__global__ __launch_bounds__(256) void k_gather40_lsm(const float* __restrict__ xw,
                                                      const float* __restrict__ b2,
                                                      float* __restrict__ out,
                                                      const int* __restrict__ rowstart,
                                                      const int* __restrict__ csr,
                                                      const float* __restrict__ dinv) {
    int node = blockIdx.x * 4 + (threadIdx.x >> 6);
    if (node >= NN) return;
    int lane = threadIdx.x & 63;
    float dd = dinv[node];
    float acc = 0.f;
    if (lane < 40) acc = dd * dd * xw[(size_t)node * 40 + lane];
    int p = rowstart[node], pe = rowstart[node + 1];
    for (; p < pe; p++) {
        int s = csr[p];
        float c = dd * dinv[s];
        if (lane < 40) acc += c * xw[(size_t)s * 40 + lane];
    }
    float v = (lane < 40) ? acc + b2[lane] : -1e30f;
    float m = v;
#pragma unroll
    for (int o = 32; o; o >>= 1) m = fmaxf(m, __shfl_xor(m, o));
    float ex = (lane < 40) ? expf(v - m) : 0.f;
    float sum = ex;
#pragma unroll
    for (int o = 32; o; o >>= 1) sum += __shfl_xor(sum, o);
    if (lane < 40) out[(size_t)node * 40 + lane] = v - m - logf(sum);
}

// ---------------- batch norm ----------------
__global__ void k_zero_stats(float* stats) {
    stats[threadIdx.x] = 0.f;  // 256 threads
}

__global__ __launch_bounds__(128) void k_bn_stats(const float* __restrict__ h,
                                                  float* __restrict__ stats) {
    int f = threadIdx.x;
    float s = 0.f, s2 = 0.f;
    for (int r = blockIdx.x; r < NN; r += gridDim.x) {
        float v = h[(size_t)r * 128 + f];
        s += v;
        s2 += v * v;
    }
    atomicAdd(&stats[f], s);
    atomicAdd(&stats[128 + f], s2);
}

__global__ void k_bn_apply(float* __restrict__ h, const float* __restrict__ stats,
                           const float* __restrict__ g, const float* __restrict__ be) {
    int gt = blockIdx.x * 256 + threadIdx.x;
    int f = gt & 127;
    float mu = stats[f] * (1.0f / NN);
    float var = stats[128 + f] * (1.0f / NN) - mu * mu;
    float sc = rsqrtf(var + EPSF) * g[f];
    float v = (h[gt] - mu) * sc + be[f];
    h[gt] = fmaxf(v, 0.0f);
}

// ---------------- launcher ----------------
extern "C" void kernel_launch(void* const* d_in, const int* in_sizes, int n_in,
                              void* d_out, int out_size, void* d_ws, size_t ws_size,
                              hipStream_t stream) {
    const float* x  = (const float*)d_in[0];
    const int* ei   = (const int*)d_in[1];
    const int* src  = ei;
    const int* dst  = ei + NE;
    const float* W0 = (const float*)d_in[2];
    const float* g0 = (const float*)d_in[4];
    const float* be0= (const float*)d_in[5];
    const float* W1 = (const float*)d_in[6];
    const float* g1 = (const float*)d_in[8];
    const float* be1= (const float*)d_in[9];
    const float* W2 = (const float*)d_in[10];
    const float* b2 = (const float*)d_in[11];
    float* out = (float*)d_out;

    // workspace layout (4-byte words)
    float* ws      = (float*)d_ws;
    float* dinv    = ws;                          // NN
    float* stats   = ws + NN;                     // 256
    int* rowstart  = (int*)(ws + NN + 256);       // NN+1
    int* cursor    = rowstart + NN + 1;           // NN   (doubles as ideg)
    int* bsum      = cursor + NN;                 // NSCAN (pad 128)
    int* csr       = bsum + 128;                  // NE
    float* bufA    = (float*)(csr + NE);          // NN*128
    float* bufB    = bufA + (size_t)NN * 128;     // NN*128

    // ---- CSR build + norm ----
    k_zero_ints<<<(NN + 255) / 256, 256, 0, stream>>>(cursor, NN);
    k_count<<<NE / 256, 256, 0, stream>>>(dst, cursor);
    k_dinv<<<(NN + 255) / 256, 256, 0, stream>>>(cursor, dinv);
    k_scan1<<<NSCAN, SCAN_BLK, 0, stream>>>(cursor, rowstart, bsum);
    k_scan2<<<1, 64, 0, stream>>>(bsum);
    k_scan3<<<NSCAN, SCAN_BLK, 0, stream>>>(rowstart, bsum);
    k_copy_ints<<<(NN + 255) / 256, 256, 0, stream>>>(rowstart, cursor);
    k_fill<<<NE / 256, 256, 0, stream>>>(src, dst, cursor, csr);

    dim3 gg((NN + 63) / 64, 2);
    int gn = (NN + 3) / 4;

    // ---- layer 0 ----
    k_gemm128<<<gg, 256, 0, stream>>>(x, W0, bufA, NN);
    k_gather128<<<gn, 256, 0, stream>>>(bufA, bufB, rowstart, csr, dinv);
    k_zero_stats<<<1, 256, 0, stream>>>(stats);
    k_bn_stats<<<1024, 128, 0, stream>>>(bufB, stats);
    k_bn_apply<<<NN * 128 / 256, 256, 0, stream>>>(bufB, stats, g0, be0);

    // ---- layer 1 ----
    k_gemm128<<<gg, 256, 0, stream>>>(bufB, W1, bufA, NN);
    k_gather128<<<gn, 256, 0, stream>>>(bufA, bufB, rowstart, csr, dinv);
    k_zero_stats<<<1, 256, 0, stream>>>(stats);
    k_bn_stats<<<1024, 128, 0, stream>>>(bufB, stats);
    k_bn_apply<<<NN * 128 / 256, 256, 0, stream>>>(bufB, stats, g1, be1);

    // ---- layer 2 (fused gather + bias + log_softmax) ----
    k_gemm40<<<(NN * 40 + 255) / 256, 256, 0, stream>>>(bufB, W2, bufA, NN);
    k_gather40_lsm<<<gn, 256, 0, stream>>>(bufA, b2, out, rowstart, csr, dinv);
}

// Round 3
// 880.807 us; speedup vs baseline: 7.0813x; 1.2960x over previous
//
#include <hip/hip_runtime.h>
#include <math.h>

#define NN 100000
#define NE 1600000
#define EPSF 1e-5f
#define SCAN_BLK 1024
#define NSCAN ((NN + SCAN_BLK - 1) / SCAN_BLK)   // 98

// ---------------- CSR build ----------------
__global__ void k_zero_ints(int* p, int n) {
    int i = blockIdx.x * 256 + threadIdx.x;
    if (i < n) p[i] = 0;
}

__global__ void k_count(const int* __restrict__ dst, int* __restrict__ ideg) {
    int e = blockIdx.x * 256 + threadIdx.x;
    if (e < NE) atomicAdd(&ideg[dst[e]], 1);
}

__global__ void k_dinv(const int* __restrict__ ideg, float* __restrict__ dinv) {
    int i = blockIdx.x * 256 + threadIdx.x;
    if (i < NN) dinv[i] = rsqrtf((float)(ideg[i] + 1));  // +1 self-loop
}

__global__ __launch_bounds__(SCAN_BLK) void k_scan1(const int* __restrict__ ideg,
                                                    int* __restrict__ rowstart,
                                                    int* __restrict__ bsum) {
    __shared__ int tmp[SCAN_BLK];
    int i = blockIdx.x * SCAN_BLK + threadIdx.x;
    int v = (i < NN) ? ideg[i] : 0;
    tmp[threadIdx.x] = v;
    __syncthreads();
    for (int o = 1; o < SCAN_BLK; o <<= 1) {
        int t = (threadIdx.x >= o) ? tmp[threadIdx.x - o] : 0;
        __syncthreads();
        tmp[threadIdx.x] += t;
        __syncthreads();
    }
    if (i < NN) rowstart[i] = tmp[threadIdx.x] - v;  // exclusive
    if (threadIdx.x == SCAN_BLK - 1) bsum[blockIdx.x] = tmp[SCAN_BLK - 1];
}

__global__ void k_scan2(int* bsum) {
    if (threadIdx.x == 0 && blockIdx.x == 0) {
        int run = 0;
        for (int b = 0; b < NSCAN; b++) {
            int t = bsum[b];
            bsum[b] = run;
            run += t;
        }
    }
}

__global__ __launch_bounds__(SCAN_BLK) void k_scan3(int* __restrict__ rowstart,
                                                    const int* __restrict__ bsum) {
    int i = blockIdx.x * SCAN_BLK + threadIdx.x;
    if (i < NN) rowstart[i] += bsum[blockIdx.x];
    if (i == 0) rowstart[NN] = NE;
}

__global__ void k_copy_ints(const int* __restrict__ a, int* __restrict__ b) {
    int i = blockIdx.x * 256 + threadIdx.x;
    if (i < NN) b[i] = a[i];
}

__global__ void k_fill(const int* __restrict__ src, const int* __restrict__ dst,
                       int* __restrict__ cursor, int* __restrict__ csr) {
    int e = blockIdx.x * 256 + threadIdx.x;
    if (e >= NE) return;
    int p = atomicAdd(&cursor[dst[e]], 1);
    csr[p] = src[e];
}

// ---------------- GEMM: [n,128] @ [128,128] -> [n,128], optional fused BN+ReLU on X ----------------
__global__ __launch_bounds__(256) void k_gemm128(const float* __restrict__ X,
                                                 const float* __restrict__ W,
                                                 float* __restrict__ Y, int n,
                                                 const float* __restrict__ stats,
                                                 const float* __restrict__ g,
                                                 const float* __restrict__ be) {
    __shared__ float Xl[64 * 128];
    __shared__ float Wl[128 * 64];
    __shared__ float ssc[128], ssh[128];
    int t = threadIdx.x;
    int row0 = blockIdx.x * 64;
    int col0 = blockIdx.y * 64;

    if (stats) {
        if (t < 128) {
            float mu = stats[t] * (1.0f / NN);
            float var = stats[128 + t] * (1.0f / NN) - mu * mu;
            float sc = rsqrtf(var + EPSF) * g[t];
            ssc[t] = sc;
            ssh[t] = be[t] - mu * sc;
        }
        __syncthreads();
    }

#pragma unroll
    for (int i = 0; i < 8; i++) {
        int idx = t + i * 256;
        int r = idx >> 5;
        int kq = idx & 31;
        int gr = row0 + r;
        float4 v = make_float4(0.f, 0.f, 0.f, 0.f);
        if (gr < n) v = reinterpret_cast<const float4*>(X + (size_t)gr * 128)[kq];
        if (stats) {
            float4 sc4 = reinterpret_cast<const float4*>(ssc)[kq];
            float4 sh4 = reinterpret_cast<const float4*>(ssh)[kq];
            v.x = fmaxf(fmaf(v.x, sc4.x, sh4.x), 0.f);
            v.y = fmaxf(fmaf(v.y, sc4.y, sh4.y), 0.f);
            v.z = fmaxf(fmaf(v.z, sc4.z, sh4.z), 0.f);
            v.w = fmaxf(fmaf(v.w, sc4.w, sh4.w), 0.f);
        }
        reinterpret_cast<float4*>(Xl + r * 128)[kq] = v;
    }
#pragma unroll
    for (int i = 0; i < 8; i++) {
        int idx = t + i * 256;
        int k = idx >> 4;
        int cq = idx & 15;
        reinterpret_cast<float4*>(Wl + k * 64)[cq] =
            reinterpret_cast<const float4*>(W + k * 128 + col0)[cq];
    }
    __syncthreads();

    int tx = t & 15, ty = t >> 4;
    int rb = ty * 4, cb = tx * 4;
    float acc[4][4] = {};
    for (int k = 0; k < 128; k += 4) {
        float4 xv[4], wv[4];
#pragma unroll
        for (int i = 0; i < 4; i++)
            xv[i] = *reinterpret_cast<const float4*>(Xl + (rb + i) * 128 + k);
#pragma unroll
        for (int j = 0; j < 4; j++)
            wv[j] = *reinterpret_cast<const float4*>(Wl + (k + j) * 64 + cb);
#pragma unroll
        for (int i = 0; i < 4; i++) {
            acc[i][0] += xv[i].x * wv[0].x + xv[i].y * wv[1].x + xv[i].z * wv[2].x + xv[i].w * wv[3].x;
            acc[i][1] += xv[i].x * wv[0].y + xv[i].y * wv[1].y + xv[i].z * wv[2].y + xv[i].w * wv[3].y;
            acc[i][2] += xv[i].x * wv[0].z + xv[i].y * wv[1].z + xv[i].z * wv[2].z + xv[i].w * wv[3].z;
            acc[i][3] += xv[i].x * wv[0].w + xv[i].y * wv[1].w + xv[i].z * wv[2].w + xv[i].w * wv[3].w;
        }
    }
#pragma unroll
    for (int i = 0; i < 4; i++) {
        int gr = row0 + rb + i;
        if (gr < n) {
            float4 o = make_float4(acc[i][0], acc[i][1], acc[i][2], acc[i][3]);
            *reinterpret_cast<float4*>(Y + (size_t)gr * 128 + col0 + cb) = o;
        }
    }
}

// ---------------- GEMM: [n,128] @ [128,40] -> [n,40], cols padded to 64, fused BN+ReLU ----------------
__global__ __launch_bounds__(256) void k_gemm40p(const float* __restrict__ X,
                                                 const float* __restrict__ W,
                                                 float* __restrict__ Y, int n,
                                                 const float* __restrict__ stats,
                                                 const float* __restrict__ g,
                                                 const float* __restrict__ be) {
    __shared__ float Xl[64 * 128];
    __shared__ float Wl[128 * 64];
    __shared__ float ssc[128], ssh[128];
    int t = threadIdx.x;
    int row0 = blockIdx.x * 64;

    if (t < 128) {
        float mu = stats[t] * (1.0f / NN);
        float var = stats[128 + t] * (1.0f / NN) - mu * mu;
        float sc = rsqrtf(var + EPSF) * g[t];
        ssc[t] = sc;
        ssh[t] = be[t] - mu * sc;
    }
    __syncthreads();

#pragma unroll
    for (int i = 0; i < 8; i++) {
        int idx = t + i * 256;
        int r = idx >> 5;
        int kq = idx & 31;
        int gr = row0 + r;
        float4 v = make_float4(0.f, 0.f, 0.f, 0.f);
        if (gr < n) v = reinterpret_cast<const float4*>(X + (size_t)gr * 128)[kq];
        float4 sc4 = reinterpret_cast<const float4*>(ssc)[kq];
        float4 sh4 = reinterpret_cast<const float4*>(ssh)[kq];
        v.x = fmaxf(fmaf(v.x, sc4.x, sh4.x), 0.f);
        v.y = fmaxf(fmaf(v.y, sc4.y, sh4.y), 0.f);
        v.z = fmaxf(fmaf(v.z, sc4.z, sh4.z), 0.f);
        v.w = fmaxf(fmaf(v.w, sc4.w, sh4.w), 0.f);
        reinterpret_cast<float4*>(Xl + r * 128)[kq] = v;
    }
#pragma unroll
    for (int i = 0; i < 8; i++) {
        int idx = t + i * 256;
        int k = idx >> 4;
        int cq = idx & 15;   // 16 float4 groups = 64 cols; only 10 valid (40 cols)
        float4 v = make_float4(0.f, 0.f, 0.f, 0.f);
        if (cq < 10) v = reinterpret_cast<const float4*>(W + k * 40)[cq];
        reinterpret_cast<float4*>(Wl + k * 64)[cq] = v;
    }
    __syncthreads();

    int tx = t & 15, ty = t >> 4;
    int rb = ty * 4, cb = tx * 4;
    float acc[4][4] = {};
    for (int k = 0; k < 128; k += 4) {
        float4 xv[4], wv[4];
#pragma unroll
        for (int i = 0; i < 4; i++)
            xv[i] = *reinterpret_cast<const float4*>(Xl + (rb + i) * 128 + k);
#pragma unroll
        for (int j = 0; j < 4; j++)
            wv[j] = *reinterpret_cast<const float4*>(Wl + (k + j) * 64 + cb);
#pragma unroll
        for (int i = 0; i < 4; i++) {
            acc[i][0] += xv[i].x * wv[0].x + xv[i].y * wv[1].x + xv[i].z * wv[2].x + xv[i].w * wv[3].x;
            acc[i][1] += xv[i].x * wv[0].y + xv[i].y * wv[1].y + xv[i].z * wv[2].y + xv[i].w * wv[3].y;
            acc[i][2] += xv[i].x * wv[0].z + xv[i].y * wv[1].z + xv[i].z * wv[2].z + xv[i].w * wv[3].z;
            acc[i][3] += xv[i].x * wv[0].w + xv[i].y * wv[1].w + xv[i].z * wv[2].w + xv[i].w * wv[3].w;
        }
    }
    if (tx < 10) {
#pragma unroll
        for (int i = 0; i < 4; i++) {
            int gr = row0 + rb + i;
            if (gr < n) {
                float4 o = make_float4(acc[i][0], acc[i][1], acc[i][2], acc[i][3]);
                *reinterpret_cast<float4*>(Y + (size_t)gr * 40 + cb) = o;
            }
        }
    }
}

// ---------------- CSR gather, 128 features (self-loop fused) ----------------
__global__ __launch_bounds__(256) void k_gather128(const float* __restrict__ xw,
                                                   float* __restrict__ agg,
                                                   const int* __restrict__ rowstart,
                                                   const int* __restrict__ csr,
                                                   const float* __restrict__ dinv) {
    int node = blockIdx.x * 4 + (threadIdx.x >> 6);
    if (node >= NN) return;
    int lane = threadIdx.x & 63;
    float dd = dinv[node];
    float2 self = reinterpret_cast<const float2*>(xw + (size_t)node * 128)[lane];
    float2 acc = make_float2(dd * dd * self.x, dd * dd * self.y);
    int p = rowstart[node], pe = rowstart[node + 1];
    for (; p + 4 <= pe; p += 4) {
        int s0 = csr[p], s1 = csr[p + 1], s2 = csr[p + 2], s3 = csr[p + 3];
        float c0 = dd * dinv[s0], c1 = dd * dinv[s1];
        float c2 = dd * dinv[s2], c3 = dd * dinv[s3];
        float2 v0 = reinterpret_cast<const float2*>(xw + (size_t)s0 * 128)[lane];
        float2 v1 = reinterpret_cast<const float2*>(xw + (size_t)s1 * 128)[lane];
        float2 v2 = reinterpret_cast<const float2*>(xw + (size_t)s2 * 128)[lane];
        float2 v3 = reinterpret_cast<const float2*>(xw + (size_t)s3 * 128)[lane];
        acc.x += c0 * v0.x + c1 * v1.x + c2 * v2.x + c3 * v3.x;
        acc.y += c0 * v0.y + c1 * v1.y + c2 * v2.y + c3 * v3.y;
    }
    for (; p < pe; p++) {
        int s = csr[p];
        float c = dd * dinv[s];
        float2 v = reinterpret_cast<const float2*>(xw + (size_t)s * 128)[lane];
        acc.x += c * v.x;
        acc.y += c * v.y;
    }
    reinterpret_cast<float2*>(agg + (size_t)node * 128)[lane] = acc;
}

// ---------------- CSR gather 40 + bias + log_softmax (fused) ----------------
__global__ __launch_bounds__(256) void k_gather40_lsm(const float* __restrict__ xw,
                                                      const float* __restrict__ b2,
                                                      float* __restrict__ out,
                                                      const int* __restrict__ rowstart,
                                                      const int* __restrict__ csr,
                                                      const float* __restrict__ dinv) {
    int node = blockIdx.x * 4 + (threadIdx.x >> 6);
    if (node >= NN) return;
    int lane = threadIdx.x & 63;
    float dd = dinv[node];
    float acc = 0.f;
    if (lane < 40) acc = dd * dd * xw[(size_t)node * 40 + lane];
    int p = rowstart[node], pe = rowstart[node + 1];
    for (; p + 2 <= pe; p += 2) {
        int sA = csr[p], sB = csr[p + 1];
        float cA = dd * dinv[sA], cB = dd * dinv[sB];
        float vA = 0.f, vB = 0.f;
        if (lane < 40) {
            vA = xw[(size_t)sA * 40 + lane];
            vB = xw[(size_t)sB * 40 + lane];
        }
        acc += cA * vA + cB * vB;
    }
    if (p < pe) {
        int s = csr[p];
        float c = dd * dinv[s];
        if (lane < 40) acc += c * xw[(size_t)s * 40 + lane];
    }
    float v = (lane < 40) ? acc + b2[lane] : -1e30f;
    float m = v;
#pragma unroll
    for (int o = 32; o; o >>= 1) m = fmaxf(m, __shfl_xor(m, o));
    float ex = (lane < 40) ? expf(v - m) : 0.f;
    float sum = ex;
#pragma unroll
    for (int o = 32; o; o >>= 1) sum += __shfl_xor(sum, o);
    if (lane < 40) out[(size_t)node * 40 + lane] = v - m - logf(sum);
}

// ---------------- batch norm stats ----------------
__global__ void k_zero_stats(float* stats) {
    stats[threadIdx.x] = 0.f;  // 256 threads
}

__global__ __launch_bounds__(128) void k_bn_stats(const float* __restrict__ h,
                                                  float* __restrict__ stats) {
    int f = threadIdx.x;
    float s = 0.f, s2 = 0.f;
    for (int r = blockIdx.x; r < NN; r += gridDim.x) {
        float v = h[(size_t)r * 128 + f];
        s += v;
        s2 += v * v;
    }
    atomicAdd(&stats[f], s);
    atomicAdd(&stats[128 + f], s2);
}

// ---------------- launcher ----------------
extern "C" void kernel_launch(void* const* d_in, const int* in_sizes, int n_in,
                              void* d_out, int out_size, void* d_ws, size_t ws_size,
                              hipStream_t stream) {
    const float* x  = (const float*)d_in[0];
    const int* ei   = (const int*)d_in[1];
    const int* src  = ei;
    const int* dst  = ei + NE;
    const float* W0 = (const float*)d_in[2];
    const float* g0 = (const float*)d_in[4];
    const float* be0= (const float*)d_in[5];
    const float* W1 = (const float*)d_in[6];
    const float* g1 = (const float*)d_in[8];
    const float* be1= (const float*)d_in[9];
    const float* W2 = (const float*)d_in[10];
    const float* b2 = (const float*)d_in[11];
    float* out = (float*)d_out;

    // workspace layout (4-byte words)
    float* ws      = (float*)d_ws;
    float* dinv    = ws;                          // NN
    float* stats   = ws + NN;                     // 256
    int* rowstart  = (int*)(ws + NN + 256);       // NN+1
    int* cursor    = rowstart + NN + 1;           // NN   (doubles as ideg)
    int* bsum      = cursor + NN;                 // NSCAN (pad 128)
    int* csr       = bsum + 128;                  // NE
    float* bufA    = (float*)(csr + NE);          // NN*128
    float* bufB    = bufA + (size_t)NN * 128;     // NN*128

    // ---- CSR build + norm ----
    k_zero_ints<<<(NN + 255) / 256, 256, 0, stream>>>(cursor, NN);
    k_count<<<NE / 256, 256, 0, stream>>>(dst, cursor);
    k_dinv<<<(NN + 255) / 256, 256, 0, stream>>>(cursor, dinv);
    k_scan1<<<NSCAN, SCAN_BLK, 0, stream>>>(cursor, rowstart, bsum);
    k_scan2<<<1, 64, 0, stream>>>(bsum);
    k_scan3<<<NSCAN, SCAN_BLK, 0, stream>>>(rowstart, bsum);
    k_copy_ints<<<(NN + 255) / 256, 256, 0, stream>>>(rowstart, cursor);
    k_fill<<<NE / 256, 256, 0, stream>>>(src, dst, cursor, csr);

    dim3 gg((NN + 63) / 64, 2);
    int gn = (NN + 3) / 4;

    // ---- layer 0 ----
    k_gemm128<<<gg, 256, 0, stream>>>(x, W0, bufA, NN, nullptr, nullptr, nullptr);
    k_gather128<<<gn, 256, 0, stream>>>(bufA, bufB, rowstart, csr, dinv);
    k_zero_stats<<<1, 256, 0, stream>>>(stats);
    k_bn_stats<<<1024, 128, 0, stream>>>(bufB, stats);

    // ---- layer 1 (BN0+ReLU fused into GEMM X-staging) ----
    k_gemm128<<<gg, 256, 0, stream>>>(bufB, W1, bufA, NN, stats, g0, be0);
    k_gather128<<<gn, 256, 0, stream>>>(bufA, bufB, rowstart, csr, dinv);
    k_zero_stats<<<1, 256, 0, stream>>>(stats);
    k_bn_stats<<<1024, 128, 0, stream>>>(bufB, stats);

    // ---- layer 2 (BN1+ReLU fused into GEMM; gather + bias + log_softmax fused) ----
    k_gemm40p<<<(NN + 63) / 64, 256, 0, stream>>>(bufB, W2, bufA, NN, stats, g1, be1);
    k_gather40_lsm<<<gn, 256, 0, stream>>>(bufA, b2, out, rowstart, csr, dinv);
}

// Round 4
// 757.931 us; speedup vs baseline: 8.2293x; 1.1621x over previous
//
#include <hip/hip_runtime.h>
#include <math.h>

#define NN 100000
#define NE 1600000
#define EPSF 1e-5f
#define SCAN_BLK 1024
#define NSCAN ((NN + SCAN_BLK - 1) / SCAN_BLK)   // 98

typedef unsigned short u16;
typedef unsigned int u32;

__device__ __forceinline__ u16 f2bf(float f) {
    u32 u = __float_as_uint(f);
    u32 r = (u + 0x7fffu + ((u >> 16) & 1u)) >> 16;   // RNE
    return (u16)r;
}
__device__ __forceinline__ float bf_lo(u32 u) { return __uint_as_float(u << 16); }
__device__ __forceinline__ float bf_hi(u32 u) { return __uint_as_float(u & 0xffff0000u); }

// ---------------- CSR build ----------------
__global__ void k_zero_ints(int* p, int n) {
    int i = blockIdx.x * 256 + threadIdx.x;
    if (i < n) p[i] = 0;
}

__global__ void k_count(const int* __restrict__ dst, int* __restrict__ ideg) {
    int e = blockIdx.x * 256 + threadIdx.x;
    if (e < NE) atomicAdd(&ideg[dst[e]], 1);
}

__global__ void k_dinv(const int* __restrict__ ideg, float* __restrict__ dinv) {
    int i = blockIdx.x * 256 + threadIdx.x;
    if (i < NN) dinv[i] = rsqrtf((float)(ideg[i] + 1));  // +1 self-loop
}

__global__ __launch_bounds__(SCAN_BLK) void k_scan1(const int* __restrict__ ideg,
                                                    int* __restrict__ rowstart,
                                                    int* __restrict__ bsum) {
    __shared__ int tmp[SCAN_BLK];
    int i = blockIdx.x * SCAN_BLK + threadIdx.x;
    int v = (i < NN) ? ideg[i] : 0;
    tmp[threadIdx.x] = v;
    __syncthreads();
    for (int o = 1; o < SCAN_BLK; o <<= 1) {
        int t = (threadIdx.x >= o) ? tmp[threadIdx.x - o] : 0;
        __syncthreads();
        tmp[threadIdx.x] += t;
        __syncthreads();
    }
    if (i < NN) rowstart[i] = tmp[threadIdx.x] - v;  // exclusive
    if (threadIdx.x == SCAN_BLK - 1) bsum[blockIdx.x] = tmp[SCAN_BLK - 1];
}

__global__ void k_scan2(int* bsum) {
    if (threadIdx.x == 0 && blockIdx.x == 0) {
        int run = 0;
        for (int b = 0; b < NSCAN; b++) {
            int t = bsum[b];
            bsum[b] = run;
            run += t;
        }
    }
}

__global__ __launch_bounds__(SCAN_BLK) void k_scan3(int* __restrict__ rowstart,
                                                    const int* __restrict__ bsum) {
    int i = blockIdx.x * SCAN_BLK + threadIdx.x;
    if (i < NN) rowstart[i] += bsum[blockIdx.x];
    if (i == 0) rowstart[NN] = NE;
}

__global__ void k_copy_ints(const int* __restrict__ a, int* __restrict__ b) {
    int i = blockIdx.x * 256 + threadIdx.x;
    if (i < NN) b[i] = a[i];
}

__global__ void k_fill(const int* __restrict__ src, const int* __restrict__ dst,
                       int* __restrict__ cursor, int* __restrict__ csr) {
    int e = blockIdx.x * 256 + threadIdx.x;
    if (e >= NE) return;
    int p = atomicAdd(&cursor[dst[e]], 1);
    csr[p] = src[e];
}

// ---------------- GEMM: [n,128] @ [128,128] -> bf16 [n,128], optional fused BN+ReLU on X ----------------
__global__ __launch_bounds__(256) void k_gemm128(const float* __restrict__ X,
                                                 const float* __restrict__ W,
                                                 u16* __restrict__ Y, int n,
                                                 const float* __restrict__ stats,
                                                 const float* __restrict__ g,
                                                 const float* __restrict__ be) {
    __shared__ float Xl[64 * 128];
    __shared__ float Wl[128 * 64];
    __shared__ float ssc[128], ssh[128];
    int t = threadIdx.x;
    int row0 = blockIdx.x * 64;
    int col0 = blockIdx.y * 64;

    if (stats) {
        if (t < 128) {
            float mu = stats[t] * (1.0f / NN);
            float var = stats[128 + t] * (1.0f / NN) - mu * mu;
            float sc = rsqrtf(var + EPSF) * g[t];
            ssc[t] = sc;
            ssh[t] = be[t] - mu * sc;
        }
        __syncthreads();
    }

#pragma unroll
    for (int i = 0; i < 8; i++) {
        int idx = t + i * 256;
        int r = idx >> 5;
        int kq = idx & 31;
        int gr = row0 + r;
        float4 v = make_float4(0.f, 0.f, 0.f, 0.f);
        if (gr < n) v = reinterpret_cast<const float4*>(X + (size_t)gr * 128)[kq];
        if (stats) {
            float4 sc4 = reinterpret_cast<const float4*>(ssc)[kq];
            float4 sh4 = reinterpret_cast<const float4*>(ssh)[kq];
            v.x = fmaxf(fmaf(v.x, sc4.x, sh4.x), 0.f);
            v.y = fmaxf(fmaf(v.y, sc4.y, sh4.y), 0.f);
            v.z = fmaxf(fmaf(v.z, sc4.z, sh4.z), 0.f);
            v.w = fmaxf(fmaf(v.w, sc4.w, sh4.w), 0.f);
        }
        reinterpret_cast<float4*>(Xl + r * 128)[kq] = v;
    }
#pragma unroll
    for (int i = 0; i < 8; i++) {
        int idx = t + i * 256;
        int k = idx >> 4;
        int cq = idx & 15;
        reinterpret_cast<float4*>(Wl + k * 64)[cq] =
            reinterpret_cast<const float4*>(W + k * 128 + col0)[cq];
    }
    __syncthreads();

    int tx = t & 15, ty = t >> 4;
    int rb = ty * 4, cb = tx * 4;
    float acc[4][4] = {};
    for (int k = 0; k < 128; k += 4) {
        float4 xv[4], wv[4];
#pragma unroll
        for (int i = 0; i < 4; i++)
            xv[i] = *reinterpret_cast<const float4*>(Xl + (rb + i) * 128 + k);
#pragma unroll
        for (int j = 0; j < 4; j++)
            wv[j] = *reinterpret_cast<const float4*>(Wl + (k + j) * 64 + cb);
#pragma unroll
        for (int i = 0; i < 4; i++) {
            acc[i][0] += xv[i].x * wv[0].x + xv[i].y * wv[1].x + xv[i].z * wv[2].x + xv[i].w * wv[3].x;
            acc[i][1] += xv[i].x * wv[0].y + xv[i].y * wv[1].y + xv[i].z * wv[2].y + xv[i].w * wv[3].y;
            acc[i][2] += xv[i].x * wv[0].z + xv[i].y * wv[1].z + xv[i].z * wv[2].z + xv[i].w * wv[3].z;
            acc[i][3] += xv[i].x * wv[0].w + xv[i].y * wv[1].w + xv[i].z * wv[2].w + xv[i].w * wv[3].w;
        }
    }
#pragma unroll
    for (int i = 0; i < 4; i++) {
        int gr = row0 + rb + i;
        if (gr < n) {
            ushort4 o;
            o.x = f2bf(acc[i][0]);
            o.y = f2bf(acc[i][1]);
            o.z = f2bf(acc[i][2]);
            o.w = f2bf(acc[i][3]);
            *reinterpret_cast<ushort4*>(Y + (size_t)gr * 128 + col0 + cb) = o;
        }
    }
}

// ---------------- GEMM: [n,128] @ [128,40] -> bf16 [n,40], fused BN+ReLU ----------------
__global__ __launch_bounds__(256) void k_gemm40p(const float* __restrict__ X,
                                                 const float* __restrict__ W,
                                                 u16* __restrict__ Y, int n,
                                                 const float* __restrict__ stats,
                                                 const float* __restrict__ g,
                                                 const float* __restrict__ be) {
    __shared__ float Xl[64 * 128];
    __shared__ float Wl[128 * 64];
    __shared__ float ssc[128], ssh[128];
    int t = threadIdx.x;
    int row0 = blockIdx.x * 64;

    if (t < 128) {
        float mu = stats[t] * (1.0f / NN);
        float var = stats[128 + t] * (1.0f / NN) - mu * mu;
        float sc = rsqrtf(var + EPSF) * g[t];
        ssc[t] = sc;
        ssh[t] = be[t] - mu * sc;
    }
    __syncthreads();

#pragma unroll
    for (int i = 0; i < 8; i++) {
        int idx = t + i * 256;
        int r = idx >> 5;
        int kq = idx & 31;
        int gr = row0 + r;
        float4 v = make_float4(0.f, 0.f, 0.f, 0.f);
        if (gr < n) v = reinterpret_cast<const float4*>(X + (size_t)gr * 128)[kq];
        float4 sc4 = reinterpret_cast<const float4*>(ssc)[kq];
        float4 sh4 = reinterpret_cast<const float4*>(ssh)[kq];
        v.x = fmaxf(fmaf(v.x, sc4.x, sh4.x), 0.f);
        v.y = fmaxf(fmaf(v.y, sc4.y, sh4.y), 0.f);
        v.z = fmaxf(fmaf(v.z, sc4.z, sh4.z), 0.f);
        v.w = fmaxf(fmaf(v.w, sc4.w, sh4.w), 0.f);
        reinterpret_cast<float4*>(Xl + r * 128)[kq] = v;
    }
#pragma unroll
    for (int i = 0; i < 8; i++) {
        int idx = t + i * 256;
        int k = idx >> 4;
        int cq = idx & 15;   // 64 padded cols; only 10 float4 groups valid (40 cols)
        float4 v = make_float4(0.f, 0.f, 0.f, 0.f);
        if (cq < 10) v = reinterpret_cast<const float4*>(W + k * 40)[cq];
        reinterpret_cast<float4*>(Wl + k * 64)[cq] = v;
    }
    __syncthreads();

    int tx = t & 15, ty = t >> 4;
    int rb = ty * 4, cb = tx * 4;
    float acc[4][4] = {};
    for (int k = 0; k < 128; k += 4) {
        float4 xv[4], wv[4];
#pragma unroll
        for (int i = 0; i < 4; i++)
            xv[i] = *reinterpret_cast<const float4*>(Xl + (rb + i) * 128 + k);
#pragma unroll
        for (int j = 0; j < 4; j++)
            wv[j] = *reinterpret_cast<const float4*>(Wl + (k + j) * 64 + cb);
#pragma unroll
        for (int i = 0; i < 4; i++) {
            acc[i][0] += xv[i].x * wv[0].x + xv[i].y * wv[1].x + xv[i].z * wv[2].x + xv[i].w * wv[3].x;
            acc[i][1] += xv[i].x * wv[0].y + xv[i].y * wv[1].y + xv[i].z * wv[2].y + xv[i].w * wv[3].y;
            acc[i][2] += xv[i].x * wv[0].z + xv[i].y * wv[1].z + xv[i].z * wv[2].z + xv[i].w * wv[3].z;
            acc[i][3] += xv[i].x * wv[0].w + xv[i].y * wv[1].w + xv[i].z * wv[2].w + xv[i].w * wv[3].w;
        }
    }
    if (tx < 10) {
#pragma unroll
        for (int i = 0; i < 4; i++) {
            int gr = row0 + rb + i;
            if (gr < n) {
                ushort4 o;
                o.x = f2bf(acc[i][0]);
                o.y = f2bf(acc[i][1]);
                o.z = f2bf(acc[i][2]);
                o.w = f2bf(acc[i][3]);
                *reinterpret_cast<ushort4*>(Y + (size_t)gr * 40 + cb) = o;
            }
        }
    }
}

// ---------------- CSR gather, 128 bf16 features (self-loop fused), fp32 out ----------------
__global__ __launch_bounds__(256) void k_gather128(const u32* __restrict__ xwb,
                                                   float* __restrict__ agg,
                                                   const int* __restrict__ rowstart,
                                                   const int* __restrict__ csr,
                                                   const float* __restrict__ dinv) {
    int node = blockIdx.x * 4 + (threadIdx.x >> 6);
    if (node >= NN) return;
    int lane = threadIdx.x & 63;
    float dd = dinv[node];
    u32 us = xwb[(size_t)node * 64 + lane];
    float2 acc = make_float2(dd * dd * bf_lo(us), dd * dd * bf_hi(us));
    int p = rowstart[node], pe = rowstart[node + 1];
    for (; p + 4 <= pe; p += 4) {
        int s0 = csr[p], s1 = csr[p + 1], s2 = csr[p + 2], s3 = csr[p + 3];
        float c0 = dd * dinv[s0], c1 = dd * dinv[s1];
        float c2 = dd * dinv[s2], c3 = dd * dinv[s3];
        u32 u0 = xwb[(size_t)s0 * 64 + lane];
        u32 u1 = xwb[(size_t)s1 * 64 + lane];
        u32 u2 = xwb[(size_t)s2 * 64 + lane];
        u32 u3 = xwb[(size_t)s3 * 64 + lane];
        acc.x += c0 * bf_lo(u0) + c1 * bf_lo(u1) + c2 * bf_lo(u2) + c3 * bf_lo(u3);
        acc.y += c0 * bf_hi(u0) + c1 * bf_hi(u1) + c2 * bf_hi(u2) + c3 * bf_hi(u3);
    }
    for (; p < pe; p++) {
        int s = csr[p];
        float c = dd * dinv[s];
        u32 u = xwb[(size_t)s * 64 + lane];
        acc.x += c * bf_lo(u);
        acc.y += c * bf_hi(u);
    }
    reinterpret_cast<float2*>(agg + (size_t)node * 128)[lane] = acc;
}

// ---------------- CSR gather 40 (bf16) + bias + log_softmax (fused) ----------------
__global__ __launch_bounds__(256) void k_gather40_lsm(const u16* __restrict__ xwb,
                                                      const float* __restrict__ b2,
                                                      float* __restrict__ out,
                                                      const int* __restrict__ rowstart,
                                                      const int* __restrict__ csr,
                                                      const float* __restrict__ dinv) {
    int node = blockIdx.x * 4 + (threadIdx.x >> 6);
    if (node >= NN) return;
    int lane = threadIdx.x & 63;
    float dd = dinv[node];
    float acc = 0.f;
    if (lane < 40) acc = dd * dd * __uint_as_float((u32)xwb[(size_t)node * 40 + lane] << 16);
    int p = rowstart[node], pe = rowstart[node + 1];
    for (; p + 2 <= pe; p += 2) {
        int sA = csr[p], sB = csr[p + 1];
        float cA = dd * dinv[sA], cB = dd * dinv[sB];
        float vA = 0.f, vB = 0.f;
        if (lane < 40) {
            vA = __uint_as_float((u32)xwb[(size_t)sA * 40 + lane] << 16);
            vB = __uint_as_float((u32)xwb[(size_t)sB * 40 + lane] << 16);
        }
        acc += cA * vA + cB * vB;
    }
    if (p < pe) {
        int s = csr[p];
        float c = dd * dinv[s];
        if (lane < 40) acc += c * __uint_as_float((u32)xwb[(size_t)s * 40 + lane] << 16);
    }
    float v = (lane < 40) ? acc + b2[lane] : -1e30f;
    float m = v;
#pragma unroll
    for (int o = 32; o; o >>= 1) m = fmaxf(m, __shfl_xor(m, o));
    float ex = (lane < 40) ? expf(v - m) : 0.f;
    float sum = ex;
#pragma unroll
    for (int o = 32; o; o >>= 1) sum += __shfl_xor(sum, o);
    if (lane < 40) out[(size_t)node * 40 + lane] = v - m - logf(sum);
}

// ---------------- batch norm stats ----------------
__global__ void k_zero_stats(float* stats) {
    stats[threadIdx.x] = 0.f;  // 256 threads
}

__global__ __launch_bounds__(128) void k_bn_stats(const float* __restrict__ h,
                                                  float* __restrict__ stats) {
    int f = threadIdx.x;
    float s = 0.f, s2 = 0.f;
    for (int r = blockIdx.x; r < NN; r += gridDim.x) {
        float v = h[(size_t)r * 128 + f];
        s += v;
        s2 += v * v;
    }
    atomicAdd(&stats[f], s);
    atomicAdd(&stats[128 + f], s2);
}

// ---------------- launcher ----------------
extern "C" void kernel_launch(void* const* d_in, const int* in_sizes, int n_in,
                              void* d_out, int out_size, void* d_ws, size_t ws_size,
                              hipStream_t stream) {
    const float* x  = (const float*)d_in[0];
    const int* ei   = (const int*)d_in[1];
    const int* src  = ei;
    const int* dst  = ei + NE;
    const float* W0 = (const float*)d_in[2];
    const float* g0 = (const float*)d_in[4];
    const float* be0= (const float*)d_in[5];
    const float* W1 = (const float*)d_in[6];
    const float* g1 = (const float*)d_in[8];
    const float* be1= (const float*)d_in[9];
    const float* W2 = (const float*)d_in[10];
    const float* b2 = (const float*)d_in[11];
    float* out = (float*)d_out;

    // workspace layout (4-byte words)
    float* ws      = (float*)d_ws;
    float* dinv    = ws;                          // NN
    float* stats   = ws + NN;                     // 256
    int* rowstart  = (int*)(ws + NN + 256);       // NN+1
    int* cursor    = rowstart + NN + 1;           // NN   (doubles as ideg)
    int* bsum      = cursor + NN;                 // 128
    int* csr       = bsum + 128;                  // NE
    u16* bufA16    = (u16*)(csr + NE);            // NN*128 bf16 (25.6 MB; layer2 reuses as NN*40)
    float* bufB    = (float*)(bufA16 + (size_t)NN * 128);  // NN*128 fp32

    // ---- CSR build + norm ----
    k_zero_ints<<<(NN + 255) / 256, 256, 0, stream>>>(cursor, NN);
    k_count<<<NE / 256, 256, 0, stream>>>(dst, cursor);
    k_dinv<<<(NN + 255) / 256, 256, 0, stream>>>(cursor, dinv);
    k_scan1<<<NSCAN, SCAN_BLK, 0, stream>>>(cursor, rowstart, bsum);
    k_scan2<<<1, 64, 0, stream>>>(bsum);
    k_scan3<<<NSCAN, SCAN_BLK, 0, stream>>>(rowstart, bsum);
    k_copy_ints<<<(NN + 255) / 256, 256, 0, stream>>>(rowstart, cursor);
    k_fill<<<NE / 256, 256, 0, stream>>>(src, dst, cursor, csr);

    dim3 gg((NN + 63) / 64, 2);
    int gn = (NN + 3) / 4;

    // ---- layer 0 ----
    k_gemm128<<<gg, 256, 0, stream>>>(x, W0, bufA16, NN, nullptr, nullptr, nullptr);
    k_gather128<<<gn, 256, 0, stream>>>((const u32*)bufA16, bufB, rowstart, csr, dinv);
    k_zero_stats<<<1, 256, 0, stream>>>(stats);
    k_bn_stats<<<1024, 128, 0, stream>>>(bufB, stats);

    // ---- layer 1 (BN0+ReLU fused into GEMM X-staging) ----
    k_gemm128<<<gg, 256, 0, stream>>>(bufB, W1, bufA16, NN, stats, g0, be0);
    k_gather128<<<gn, 256, 0, stream>>>((const u32*)bufA16, bufB, rowstart, csr, dinv);
    k_zero_stats<<<1, 256, 0, stream>>>(stats);
    k_bn_stats<<<1024, 128, 0, stream>>>(bufB, stats);

    // ---- layer 2 (BN1+ReLU fused into GEMM; gather + bias + log_softmax fused) ----
    k_gemm40p<<<(NN + 63) / 64, 256, 0, stream>>>(bufB, W2, bufA16, NN, stats, g1, be1);
    k_gather40_lsm<<<gn, 256, 0, stream>>>(bufA16, b2, out, rowstart, csr, dinv);
}

// Round 7
// 641.012 us; speedup vs baseline: 9.7303x; 1.1824x over previous
//
#include <hip/hip_runtime.h>
#include <math.h>

#define NN 100000
#define NE 1600000
#define EPSF 1e-5f
#define NB 196          // buckets of 512 nodes
#define BKN 512
#define CHA 8192        // edges per block in bucket passes

typedef unsigned short u16;
typedef unsigned int u32;

__device__ __forceinline__ u16 f2bf(float f) {
    u32 u = __float_as_uint(f);
    u32 r = (u + 0x7fffu + ((u >> 16) & 1u)) >> 16;   // RNE
    return (u16)r;
}
__device__ __forceinline__ float bf_lo(u32 u) { return __uint_as_float(u << 16); }
__device__ __forceinline__ float bf_hi(u32 u) { return __uint_as_float(u & 0xffff0000u); }

// ---------------- misc ----------------
__global__ void k_zero_ints(int* p, int n) {
    int i = blockIdx.x * 256 + threadIdx.x;
    if (i < n) p[i] = 0;
}

__global__ void k_zero_stats(float* stats) {
    stats[threadIdx.x] = 0.f;  // 256 threads
}

// ---------------- CSR build pass A1: per-bucket edge counts ----------------
__global__ __launch_bounds__(256) void k_bcount(const int* __restrict__ dst,
                                                int* __restrict__ gcnt) {
    __shared__ int hist[NB];
    int t = threadIdx.x;
    long e0 = (long)blockIdx.x * CHA;
    for (int i = t; i < NB; i += 256) hist[i] = 0;
    __syncthreads();
#pragma unroll
    for (int i = 0; i < CHA / 256; i++) {
        long e = e0 + i * 256 + t;
        if (e < NE) atomicAdd(&hist[dst[e] >> 9], 1);
    }
    __syncthreads();
    for (int i = t; i < NB; i += 256)
        if (hist[i]) atomicAdd(&gcnt[i], hist[i]);
}

__global__ void k_scanbkt(const int* __restrict__ gcnt, int* __restrict__ bktbase) {
    if (threadIdx.x == 0 && blockIdx.x == 0) {
        int run = 0;
        for (int b = 0; b < NB; b++) { bktbase[b] = run; run += gcnt[b]; }
        bktbase[NB] = run;  // = NE
    }
}

// ---------------- CSR build pass A2: scatter edges into bucket-major order ----------------
__global__ __launch_bounds__(256) void k_bscatter(const int* __restrict__ src,
                                                  const int* __restrict__ dst,
                                                  const int* __restrict__ bktbase,
                                                  int* __restrict__ gcur,
                                                  u32* __restrict__ bkt) {
    __shared__ int hist[NB];
    __shared__ int base[NB];
    int t = threadIdx.x;
    long e0 = (long)blockIdx.x * CHA;
    for (int i = t; i < NB; i += 256) hist[i] = 0;
    __syncthreads();
#pragma unroll
    for (int i = 0; i < CHA / 256; i++) {
        long e = e0 + i * 256 + t;
        if (e < NE) atomicAdd(&hist[dst[e] >> 9], 1);
    }
    __syncthreads();
    // reserve GLOBAL slots: bucket base + within-bucket running cursor
    for (int i = t; i < NB; i += 256)
        base[i] = bktbase[i] + atomicAdd(&gcur[i], hist[i]);
    __syncthreads();
    for (int i = t; i < NB; i += 256) hist[i] = 0;
    __syncthreads();
#pragma unroll
    for (int i = 0; i < CHA / 256; i++) {
        long e = e0 + i * 256 + t;
        if (e < NE) {
            int d = dst[e];
            int s = src[e];
            int b = d >> 9;
            int r = atomicAdd(&hist[b], 1);
            bkt[base[b] + r] = (u32)s | ((u32)(d & 511) << 17);
        }
    }
}

// ---------------- CSR build pass B (per-bucket hist+scan+fill; also dinv) ----------------
__global__ __launch_bounds__(BKN) void k_csr(const u32* __restrict__ bkt,
                                             const int* __restrict__ bktbase,
                                             int* __restrict__ rowstart,
                                             int* __restrict__ csr,
                                             float* __restrict__ dinv) {
    __shared__ int cnt[BKN];
    __shared__ int tmp[BKN];
    __shared__ int cur[BKN];
    int t = threadIdx.x, b = blockIdx.x;
    int n0 = b * BKN;
    int ebase = bktbase[b];
    int m = bktbase[b + 1] - ebase;
    cnt[t] = 0;
    __syncthreads();
    for (int i = t; i < m; i += BKN)
        atomicAdd(&cnt[(bkt[ebase + i] >> 17) & 511], 1);
    __syncthreads();
    int v = cnt[t];
    tmp[t] = v;
    __syncthreads();
    for (int o = 1; o < BKN; o <<= 1) {
        int u = (t >= o) ? tmp[t - o] : 0;
        __syncthreads();
        tmp[t] += u;
        __syncthreads();
    }
    int excl = tmp[t] - v;
    int node = n0 + t;
    if (node < NN) {
        rowstart[node] = ebase + excl;
        dinv[node] = rsqrtf((float)(v + 1));
    }
    if (b == NB - 1 && t == 0) rowstart[NN] = NE;
    cur[t] = ebase + excl;
    __syncthreads();
    for (int i = t; i < m; i += BKN) {
        u32 p = bkt[ebase + i];
        int pos = atomicAdd(&cur[(p >> 17) & 511], 1);
        csr[pos] = (int)(p & 0x1FFFFu);
    }
}

// ---------------- GEMM: [n,128] @ [128,128] -> bf16 [n,128], optional fused BN+ReLU on X ----------------
__global__ __launch_bounds__(256) void k_gemm128(const float* __restrict__ X,
                                                 const float* __restrict__ W,
                                                 u16* __restrict__ Y, int n,
                                                 const float* __restrict__ stats,
                                                 const float* __restrict__ g,
                                                 const float* __restrict__ be) {
    __shared__ float Xl[64 * 128];
    __shared__ float Wl[128 * 64];
    __shared__ float ssc[128], ssh[128];
    int t = threadIdx.x;
    int row0 = blockIdx.x * 64;
    int col0 = blockIdx.y * 64;

    if (stats) {
        if (t < 128) {
            float mu = stats[t] * (1.0f / NN);
            float var = stats[128 + t] * (1.0f / NN) - mu * mu;
            float sc = rsqrtf(var + EPSF) * g[t];
            ssc[t] = sc;
            ssh[t] = be[t] - mu * sc;
        }
        __syncthreads();
    }

#pragma unroll
    for (int i = 0; i < 8; i++) {
        int idx = t + i * 256;
        int r = idx >> 5;
        int kq = idx & 31;
        int gr = row0 + r;
        float4 v = make_float4(0.f, 0.f, 0.f, 0.f);
        if (gr < n) v = reinterpret_cast<const float4*>(X + (size_t)gr * 128)[kq];
        if (stats) {
            float4 sc4 = reinterpret_cast<const float4*>(ssc)[kq];
            float4 sh4 = reinterpret_cast<const float4*>(ssh)[kq];
            v.x = fmaxf(fmaf(v.x, sc4.x, sh4.x), 0.f);
            v.y = fmaxf(fmaf(v.y, sc4.y, sh4.y), 0.f);
            v.z = fmaxf(fmaf(v.z, sc4.z, sh4.z), 0.f);
            v.w = fmaxf(fmaf(v.w, sc4.w, sh4.w), 0.f);
        }
        reinterpret_cast<float4*>(Xl + r * 128)[kq] = v;
    }
#pragma unroll
    for (int i = 0; i < 8; i++) {
        int idx = t + i * 256;
        int k = idx >> 4;
        int cq = idx & 15;
        reinterpret_cast<float4*>(Wl + k * 64)[cq] =
            reinterpret_cast<const float4*>(W + k * 128 + col0)[cq];
    }
    __syncthreads();

    int tx = t & 15, ty = t >> 4;
    int rb = ty * 4, cb = tx * 4;
    float acc[4][4] = {};
    for (int k = 0; k < 128; k += 4) {
        float4 xv[4], wv[4];
#pragma unroll
        for (int i = 0; i < 4; i++)
            xv[i] = *reinterpret_cast<const float4*>(Xl + (rb + i) * 128 + k);
#pragma unroll
        for (int j = 0; j < 4; j++)
            wv[j] = *reinterpret_cast<const float4*>(Wl + (k + j) * 64 + cb);
#pragma unroll
        for (int i = 0; i < 4; i++) {
            acc[i][0] += xv[i].x * wv[0].x + xv[i].y * wv[1].x + xv[i].z * wv[2].x + xv[i].w * wv[3].x;
            acc[i][1] += xv[i].x * wv[0].y + xv[i].y * wv[1].y + xv[i].z * wv[2].y + xv[i].w * wv[3].y;
            acc[i][2] += xv[i].x * wv[0].z + xv[i].y * wv[1].z + xv[i].z * wv[2].z + xv[i].w * wv[3].z;
            acc[i][3] += xv[i].x * wv[0].w + xv[i].y * wv[1].w + xv[i].z * wv[2].w + xv[i].w * wv[3].w;
        }
    }
#pragma unroll
    for (int i = 0; i < 4; i++) {
        int gr = row0 + rb + i;
        if (gr < n) {
            ushort4 o;
            o.x = f2bf(acc[i][0]);
            o.y = f2bf(acc[i][1]);
            o.z = f2bf(acc[i][2]);
            o.w = f2bf(acc[i][3]);
            *reinterpret_cast<ushort4*>(Y + (size_t)gr * 128 + col0 + cb) = o;
        }
    }
}

// ---------------- GEMM: [n,128] @ [128,40] -> bf16 [n,40], fused BN+ReLU ----------------
__global__ __launch_bounds__(256) void k_gemm40p(const float* __restrict__ X,
                                                 const float* __restrict__ W,
                                                 u16* __restrict__ Y, int n,
                                                 const float* __restrict__ stats,
                                                 const float* __restrict__ g,
                                                 const float* __restrict__ be) {
    __shared__ float Xl[64 * 128];
    __shared__ float Wl[128 * 64];
    __shared__ float ssc[128], ssh[128];
    int t = threadIdx.x;
    int row0 = blockIdx.x * 64;

    if (t < 128) {
        float mu = stats[t] * (1.0f / NN);
        float var = stats[128 + t] * (1.0f / NN) - mu * mu;
        float sc = rsqrtf(var + EPSF) * g[t];
        ssc[t] = sc;
        ssh[t] = be[t] - mu * sc;
    }
    __syncthreads();

#pragma unroll
    for (int i = 0; i < 8; i++) {
        int idx = t + i * 256;
        int r = idx >> 5;
        int kq = idx & 31;
        int gr = row0 + r;
        float4 v = make_float4(0.f, 0.f, 0.f, 0.f);
        if (gr < n) v = reinterpret_cast<const float4*>(X + (size_t)gr * 128)[kq];
        float4 sc4 = reinterpret_cast<const float4*>(ssc)[kq];
        float4 sh4 = reinterpret_cast<const float4*>(ssh)[kq];
        v.x = fmaxf(fmaf(v.x, sc4.x, sh4.x), 0.f);
        v.y = fmaxf(fmaf(v.y, sc4.y, sh4.y), 0.f);
        v.z = fmaxf(fmaf(v.z, sc4.z, sh4.z), 0.f);
        v.w = fmaxf(fmaf(v.w, sc4.w, sh4.w), 0.f);
        reinterpret_cast<float4*>(Xl + r * 128)[kq] = v;
    }
#pragma unroll
    for (int i = 0; i < 8; i++) {
        int idx = t + i * 256;
        int k = idx >> 4;
        int cq = idx & 15;   // 64 padded cols; only 10 float4 groups valid (40 cols)
        float4 v = make_float4(0.f, 0.f, 0.f, 0.f);
        if (cq < 10) v = reinterpret_cast<const float4*>(W + k * 40)[cq];
        reinterpret_cast<float4*>(Wl + k * 64)[cq] = v;
    }
    __syncthreads();

    int tx = t & 15, ty = t >> 4;
    int rb = ty * 4, cb = tx * 4;
    float acc[4][4] = {};
    for (int k = 0; k < 128; k += 4) {
        float4 xv[4], wv[4];
#pragma unroll
        for (int i = 0; i < 4; i++)
            xv[i] = *reinterpret_cast<const float4*>(Xl + (rb + i) * 128 + k);
#pragma unroll
        for (int j = 0; j < 4; j++)
            wv[j] = *reinterpret_cast<const float4*>(Wl + (k + j) * 64 + cb);
#pragma unroll
        for (int i = 0; i < 4; i++) {
            acc[i][0] += xv[i].x * wv[0].x + xv[i].y * wv[1].x + xv[i].z * wv[2].x + xv[i].w * wv[3].x;
            acc[i][1] += xv[i].x * wv[0].y + xv[i].y * wv[1].y + xv[i].z * wv[2].y + xv[i].w * wv[3].y;
            acc[i][2] += xv[i].x * wv[0].z + xv[i].y * wv[1].z + xv[i].z * wv[2].z + xv[i].w * wv[3].z;
            acc[i][3] += xv[i].x * wv[0].w + xv[i].y * wv[1].w + xv[i].z * wv[2].w + xv[i].w * wv[3].w;
        }
    }
    if (tx < 10) {
#pragma unroll
        for (int i = 0; i < 4; i++) {
            int gr = row0 + rb + i;
            if (gr < n) {
                ushort4 o;
                o.x = f2bf(acc[i][0]);
                o.y = f2bf(acc[i][1]);
                o.z = f2bf(acc[i][2]);
                o.w = f2bf(acc[i][3]);
                *reinterpret_cast<ushort4*>(Y + (size_t)gr * 40 + cb) = o;
            }
        }
    }
}

// ---------------- CSR gather 128 bf16 (self-loop fused) + fused BN stats ----------------
// 32 nodes/block (grid 3125 = exactly NN), wave w handles nodes [nb+8w, nb+8w+8)
__global__ __launch_bounds__(256) void k_gather128s(const u32* __restrict__ xwb,
                                                    float* __restrict__ agg,
                                                    const int* __restrict__ rowstart,
                                                    const int* __restrict__ csr,
                                                    const float* __restrict__ dinv,
                                                    float* __restrict__ stats) {
    __shared__ float red[1024];  // [0..511]: sum per (wave,feat); [512..1023]: sum2
    int t = threadIdx.x;
    int w = t >> 6, l = t & 63;
    int nb = blockIdx.x * 32 + w * 8;
    float sx = 0.f, sy = 0.f, sxx = 0.f, syy = 0.f;
    for (int i = 0; i < 8; i++) {
        int node = nb + i;
        if (node >= NN) break;
        float dd = dinv[node];
        u32 us = xwb[(size_t)node * 64 + l];
        float ax = dd * dd * bf_lo(us);
        float ay = dd * dd * bf_hi(us);
        int p = rowstart[node], pe = rowstart[node + 1];
        for (; p + 4 <= pe; p += 4) {
            int s0 = csr[p], s1 = csr[p + 1], s2 = csr[p + 2], s3 = csr[p + 3];
            float c0 = dd * dinv[s0], c1 = dd * dinv[s1];
            float c2 = dd * dinv[s2], c3 = dd * dinv[s3];
            u32 u0 = xwb[(size_t)s0 * 64 + l];
            u32 u1 = xwb[(size_t)s1 * 64 + l];
            u32 u2 = xwb[(size_t)s2 * 64 + l];
            u32 u3 = xwb[(size_t)s3 * 64 + l];
            ax += c0 * bf_lo(u0) + c1 * bf_lo(u1) + c2 * bf_lo(u2) + c3 * bf_lo(u3);
            ay += c0 * bf_hi(u0) + c1 * bf_hi(u1) + c2 * bf_hi(u2) + c3 * bf_hi(u3);
        }
        for (; p < pe; p++) {
            int s = csr[p];
            float c = dd * dinv[s];
            u32 u = xwb[(size_t)s * 64 + l];
            ax += c * bf_lo(u);
            ay += c * bf_hi(u);
        }
        reinterpret_cast<float2*>(agg + (size_t)node * 128)[l] = make_float2(ax, ay);
        sx += ax; sxx += ax * ax;
        sy += ay; syy += ay * ay;
    }
    red[w * 128 + 2 * l]     = sx;
    red[w * 128 + 2 * l + 1] = sy;
    red[512 + w * 128 + 2 * l]     = sxx;
    red[512 + w * 128 + 2 * l + 1] = syy;
    __syncthreads();
    if (t < 128) {
        float s  = red[t] + red[128 + t] + red[256 + t] + red[384 + t];
        float s2 = red[512 + t] + red[640 + t] + red[768 + t] + red[896 + t];
        atomicAdd(&stats[t], s);
        atomicAdd(&stats[128 + t], s2);
    }
}

// ---------------- CSR gather 40 (bf16) + bias + log_softmax (fused) ----------------
__global__ __launch_bounds__(256) void k_gather40_lsm(const u16* __restrict__ xwb,
                                                      const float* __restrict__ b2,
                                                      float* __restrict__ out,
                                                      const int* __restrict__ rowstart,
                                                      const int* __restrict__ csr,
                                                      const float* __restrict__ dinv) {
    int node = blockIdx.x * 4 + (threadIdx.x >> 6);
    if (node >= NN) return;
    int lane = threadIdx.x & 63;
    float dd = dinv[node];
    float acc = 0.f;
    if (lane < 40) acc = dd * dd * __uint_as_float((u32)xwb[(size_t)node * 40 + lane] << 16);
    int p = rowstart[node], pe = rowstart[node + 1];
    for (; p + 2 <= pe; p += 2) {
        int sA = csr[p], sB = csr[p + 1];
        float cA = dd * dinv[sA], cB = dd * dinv[sB];
        float vA = 0.f, vB = 0.f;
        if (lane < 40) {
            vA = __uint_as_float((u32)xwb[(size_t)sA * 40 + lane] << 16);
            vB = __uint_as_float((u32)xwb[(size_t)sB * 40 + lane] << 16);
        }
        acc += cA * vA + cB * vB;
    }
    if (p < pe) {
        int s = csr[p];
        float c = dd * dinv[s];
        if (lane < 40) acc += c * __uint_as_float((u32)xwb[(size_t)s * 40 + lane] << 16);
    }
    float v = (lane < 40) ? acc + b2[lane] : -1e30f;
    float m = v;
#pragma unroll
    for (int o = 32; o; o >>= 1) m = fmaxf(m, __shfl_xor(m, o));
    float ex = (lane < 40) ? expf(v - m) : 0.f;
    float sum = ex;
#pragma unroll
    for (int o = 32; o; o >>= 1) sum += __shfl_xor(sum, o);
    if (lane < 40) out[(size_t)node * 40 + lane] = v - m - logf(sum);
}

// ---------------- launcher ----------------
extern "C" void kernel_launch(void* const* d_in, const int* in_sizes, int n_in,
                              void* d_out, int out_size, void* d_ws, size_t ws_size,
                              hipStream_t stream) {
    const float* x  = (const float*)d_in[0];
    const int* ei   = (const int*)d_in[1];
    const int* src  = ei;
    const int* dst  = ei + NE;
    const float* W0 = (const float*)d_in[2];
    const float* g0 = (const float*)d_in[4];
    const float* be0= (const float*)d_in[5];
    const float* W1 = (const float*)d_in[6];
    const float* g1 = (const float*)d_in[8];
    const float* be1= (const float*)d_in[9];
    const float* W2 = (const float*)d_in[10];
    const float* b2 = (const float*)d_in[11];
    float* out = (float*)d_out;

    // workspace layout (4-byte words), total 22,600,856 words = 90.4 MB (<110 MB proven in R2)
    // dinv      [0,         100,000)
    // stats     [100,000,   100,256)
    // rowstart  [100,256,   200,257)
    // gcnt      [200,260,   200,456)
    // gcur      [200,456,   200,652)
    // bktbase   [200,652,   200,849)  pad-> 200,856
    // bkt       [200,856, 1,800,856)
    // csr       [1,800,856, 3,400,856)
    // bufA16    [3,400,856, 9,800,856)   NN*128 bf16 = 6.4M words
    // bufB      [9,800,856, 22,600,856)  NN*128 fp32
    float* ws      = (float*)d_ws;
    float* dinv    = ws;
    float* stats   = ws + 100000;
    int* rowstart  = (int*)(ws + 100256);
    int* gcnt      = (int*)(ws + 200260);
    int* gcur      = (int*)(ws + 200456);
    int* bktbase   = (int*)(ws + 200652);
    u32* bkt       = (u32*)(ws + 200856);
    int* csr       = (int*)(ws + 1800856);
    u16* bufA16    = (u16*)(ws + 3400856);
    float* bufB    = ws + 9800856;

    // ---- CSR build (bucketized, three-pass, all global slots rebased by bktbase) ----
    k_zero_ints<<<2, 256, 0, stream>>>(gcnt, 392);  // gcnt + gcur contiguous
    k_bcount<<<(NE + CHA - 1) / CHA, 256, 0, stream>>>(dst, gcnt);
    k_scanbkt<<<1, 64, 0, stream>>>(gcnt, bktbase);
    k_bscatter<<<(NE + CHA - 1) / CHA, 256, 0, stream>>>(src, dst, bktbase, gcur, bkt);
    k_csr<<<NB, BKN, 0, stream>>>(bkt, bktbase, rowstart, csr, dinv);

    dim3 gg((NN + 63) / 64, 2);
    int gs = (NN + 31) / 32;   // gather blocks (32 nodes each) = 3125

    // ---- layer 0 ----
    k_gemm128<<<gg, 256, 0, stream>>>(x, W0, bufA16, NN, nullptr, nullptr, nullptr);
    k_zero_stats<<<1, 256, 0, stream>>>(stats);
    k_gather128s<<<gs, 256, 0, stream>>>((const u32*)bufA16, bufB, rowstart, csr, dinv, stats);

    // ---- layer 1 (BN0+ReLU fused into GEMM X-staging) ----
    k_gemm128<<<gg, 256, 0, stream>>>(bufB, W1, bufA16, NN, stats, g0, be0);
    k_zero_stats<<<1, 256, 0, stream>>>(stats);
    k_gather128s<<<gs, 256, 0, stream>>>((const u32*)bufA16, bufB, rowstart, csr, dinv, stats);

    // ---- layer 2 (BN1+ReLU fused into GEMM; gather + bias + log_softmax fused) ----
    k_gemm40p<<<(NN + 63) / 64, 256, 0, stream>>>(bufB, W2, bufA16, NN, stats, g1, be1);
    k_gather40_lsm<<<(NN + 3) / 4, 256, 0, stream>>>(bufA16, b2, out, rowstart, csr, dinv);
}

// Round 8
// 604.622 us; speedup vs baseline: 10.3159x; 1.0602x over previous
//
#include <hip/hip_runtime.h>
#include <math.h>

#define NN 100000
#define NE 1600000
#define EPSF 1e-5f
#define NB 196          // buckets of 512 nodes
#define BKN 512
#define CHA 8192        // edges per block in bucket passes

typedef unsigned short u16;
typedef unsigned int u32;

__device__ __forceinline__ u16 f2bf(float f) {
    u32 u = __float_as_uint(f);
    u32 r = (u + 0x7fffu + ((u >> 16) & 1u)) >> 16;   // RNE
    return (u16)r;
}
__device__ __forceinline__ float bf_lo(u32 u) { return __uint_as_float(u << 16); }
__device__ __forceinline__ float bf_hi(u32 u) { return __uint_as_float(u & 0xffff0000u); }

// ---------------- misc ----------------
__global__ void k_zero_ints(int* p, int n) {
    int i = blockIdx.x * 256 + threadIdx.x;
    if (i < n) p[i] = 0;
}

__global__ void k_zero_stats(float* stats) {
    stats[threadIdx.x] = 0.f;  // 256 threads
}

// ---------------- CSR build pass A1: per-bucket edge counts ----------------
__global__ __launch_bounds__(256) void k_bcount(const int* __restrict__ dst,
                                                int* __restrict__ gcnt) {
    __shared__ int hist[NB];
    int t = threadIdx.x;
    long e0 = (long)blockIdx.x * CHA;
    for (int i = t; i < NB; i += 256) hist[i] = 0;
    __syncthreads();
#pragma unroll
    for (int i = 0; i < CHA / 256; i++) {
        long e = e0 + i * 256 + t;
        if (e < NE) atomicAdd(&hist[dst[e] >> 9], 1);
    }
    __syncthreads();
    for (int i = t; i < NB; i += 256)
        if (hist[i]) atomicAdd(&gcnt[i], hist[i]);
}

__global__ void k_scanbkt(const int* __restrict__ gcnt, int* __restrict__ bktbase) {
    if (threadIdx.x == 0 && blockIdx.x == 0) {
        int run = 0;
        for (int b = 0; b < NB; b++) { bktbase[b] = run; run += gcnt[b]; }
        bktbase[NB] = run;  // = NE
    }
}

// ---------------- CSR build pass A2: scatter edges into bucket-major order ----------------
__global__ __launch_bounds__(256) void k_bscatter(const int* __restrict__ src,
                                                  const int* __restrict__ dst,
                                                  const int* __restrict__ bktbase,
                                                  int* __restrict__ gcur,
                                                  u32* __restrict__ bkt) {
    __shared__ int hist[NB];
    __shared__ int base[NB];
    int t = threadIdx.x;
    long e0 = (long)blockIdx.x * CHA;
    for (int i = t; i < NB; i += 256) hist[i] = 0;
    __syncthreads();
#pragma unroll
    for (int i = 0; i < CHA / 256; i++) {
        long e = e0 + i * 256 + t;
        if (e < NE) atomicAdd(&hist[dst[e] >> 9], 1);
    }
    __syncthreads();
    // reserve GLOBAL slots: bucket base + within-bucket running cursor
    for (int i = t; i < NB; i += 256)
        base[i] = bktbase[i] + atomicAdd(&gcur[i], hist[i]);
    __syncthreads();
    for (int i = t; i < NB; i += 256) hist[i] = 0;
    __syncthreads();
#pragma unroll
    for (int i = 0; i < CHA / 256; i++) {
        long e = e0 + i * 256 + t;
        if (e < NE) {
            int d = dst[e];
            int s = src[e];
            int b = d >> 9;
            int r = atomicAdd(&hist[b], 1);
            bkt[base[b] + r] = (u32)s | ((u32)(d & 511) << 17);
        }
    }
}

// ---------------- CSR build pass B (per-bucket hist+scan+fill; also dinv) ----------------
__global__ __launch_bounds__(BKN) void k_csr(const u32* __restrict__ bkt,
                                             const int* __restrict__ bktbase,
                                             int* __restrict__ rowstart,
                                             int* __restrict__ csr,
                                             float* __restrict__ dinv) {
    __shared__ int cnt[BKN];
    __shared__ int tmp[BKN];
    __shared__ int cur[BKN];
    int t = threadIdx.x, b = blockIdx.x;
    int n0 = b * BKN;
    int ebase = bktbase[b];
    int m = bktbase[b + 1] - ebase;
    cnt[t] = 0;
    __syncthreads();
    for (int i = t; i < m; i += BKN)
        atomicAdd(&cnt[(bkt[ebase + i] >> 17) & 511], 1);
    __syncthreads();
    int v = cnt[t];
    tmp[t] = v;
    __syncthreads();
    for (int o = 1; o < BKN; o <<= 1) {
        int u = (t >= o) ? tmp[t - o] : 0;
        __syncthreads();
        tmp[t] += u;
        __syncthreads();
    }
    int excl = tmp[t] - v;
    int node = n0 + t;
    if (node < NN) {
        rowstart[node] = ebase + excl;
        dinv[node] = rsqrtf((float)(v + 1));
    }
    if (b == NB - 1 && t == 0) rowstart[NN] = NE;
    cur[t] = ebase + excl;
    __syncthreads();
    for (int i = t; i < m; i += BKN) {
        u32 p = bkt[ebase + i];
        int pos = atomicAdd(&cur[(p >> 17) & 511], 1);
        csr[pos] = (int)(p & 0x1FFFFu);
    }
}

// ---------------- GEMM: [n,128] @ [128,128] -> bf16 [n,128], optional fused BN+ReLU on X ----------------
__global__ __launch_bounds__(256) void k_gemm128(const float* __restrict__ X,
                                                 const float* __restrict__ W,
                                                 u16* __restrict__ Y, int n,
                                                 const float* __restrict__ stats,
                                                 const float* __restrict__ g,
                                                 const float* __restrict__ be) {
    __shared__ float Xl[64 * 128];
    __shared__ float Wl[128 * 64];
    __shared__ float ssc[128], ssh[128];
    int t = threadIdx.x;
    int row0 = blockIdx.x * 64;
    int col0 = blockIdx.y * 64;

    if (stats) {
        if (t < 128) {
            float mu = stats[t] * (1.0f / NN);
            float var = stats[128 + t] * (1.0f / NN) - mu * mu;
            float sc = rsqrtf(var + EPSF) * g[t];
            ssc[t] = sc;
            ssh[t] = be[t] - mu * sc;
        }
        __syncthreads();
    }

#pragma unroll
    for (int i = 0; i < 8; i++) {
        int idx = t + i * 256;
        int r = idx >> 5;
        int kq = idx & 31;
        int gr = row0 + r;
        float4 v = make_float4(0.f, 0.f, 0.f, 0.f);
        if (gr < n) v = reinterpret_cast<const float4*>(X + (size_t)gr * 128)[kq];
        if (stats) {
            float4 sc4 = reinterpret_cast<const float4*>(ssc)[kq];
            float4 sh4 = reinterpret_cast<const float4*>(ssh)[kq];
            v.x = fmaxf(fmaf(v.x, sc4.x, sh4.x), 0.f);
            v.y = fmaxf(fmaf(v.y, sc4.y, sh4.y), 0.f);
            v.z = fmaxf(fmaf(v.z, sc4.z, sh4.z), 0.f);
            v.w = fmaxf(fmaf(v.w, sc4.w, sh4.w), 0.f);
        }
        reinterpret_cast<float4*>(Xl + r * 128)[kq] = v;
    }
#pragma unroll
    for (int i = 0; i < 8; i++) {
        int idx = t + i * 256;
        int k = idx >> 4;
        int cq = idx & 15;
        reinterpret_cast<float4*>(Wl + k * 64)[cq] =
            reinterpret_cast<const float4*>(W + k * 128 + col0)[cq];
    }
    __syncthreads();

    int tx = t & 15, ty = t >> 4;
    int rb = ty * 4, cb = tx * 4;
    float acc[4][4] = {};
    for (int k = 0; k < 128; k += 4) {
        float4 xv[4], wv[4];
#pragma unroll
        for (int i = 0; i < 4; i++)
            xv[i] = *reinterpret_cast<const float4*>(Xl + (rb + i) * 128 + k);
#pragma unroll
        for (int j = 0; j < 4; j++)
            wv[j] = *reinterpret_cast<const float4*>(Wl + (k + j) * 64 + cb);
#pragma unroll
        for (int i = 0; i < 4; i++) {
            acc[i][0] += xv[i].x * wv[0].x + xv[i].y * wv[1].x + xv[i].z * wv[2].x + xv[i].w * wv[3].x;
            acc[i][1] += xv[i].x * wv[0].y + xv[i].y * wv[1].y + xv[i].z * wv[2].y + xv[i].w * wv[3].y;
            acc[i][2] += xv[i].x * wv[0].z + xv[i].y * wv[1].z + xv[i].z * wv[2].z + xv[i].w * wv[3].z;
            acc[i][3] += xv[i].x * wv[0].w + xv[i].y * wv[1].w + xv[i].z * wv[2].w + xv[i].w * wv[3].w;
        }
    }
#pragma unroll
    for (int i = 0; i < 4; i++) {
        int gr = row0 + rb + i;
        if (gr < n) {
            ushort4 o;
            o.x = f2bf(acc[i][0]);
            o.y = f2bf(acc[i][1]);
            o.z = f2bf(acc[i][2]);
            o.w = f2bf(acc[i][3]);
            *reinterpret_cast<ushort4*>(Y + (size_t)gr * 128 + col0 + cb) = o;
        }
    }
}

// ---------------- GEMM: [n,128] @ [128,40] -> bf16 [n,40], fused BN+ReLU ----------------
__global__ __launch_bounds__(256) void k_gemm40p(const float* __restrict__ X,
                                                 const float* __restrict__ W,
                                                 u16* __restrict__ Y, int n,
                                                 const float* __restrict__ stats,
                                                 const float* __restrict__ g,
                                                 const float* __restrict__ be) {
    __shared__ float Xl[64 * 128];
    __shared__ float Wl[128 * 64];
    __shared__ float ssc[128], ssh[128];
    int t = threadIdx.x;
    int row0 = blockIdx.x * 64;

    if (t < 128) {
        float mu = stats[t] * (1.0f / NN);
        float var = stats[128 + t] * (1.0f / NN) - mu * mu;
        float sc = rsqrtf(var + EPSF) * g[t];
        ssc[t] = sc;
        ssh[t] = be[t] - mu * sc;
    }
    __syncthreads();

#pragma unroll
    for (int i = 0; i < 8; i++) {
        int idx = t + i * 256;
        int r = idx >> 5;
        int kq = idx & 31;
        int gr = row0 + r;
        float4 v = make_float4(0.f, 0.f, 0.f, 0.f);
        if (gr < n) v = reinterpret_cast<const float4*>(X + (size_t)gr * 128)[kq];
        float4 sc4 = reinterpret_cast<const float4*>(ssc)[kq];
        float4 sh4 = reinterpret_cast<const float4*>(ssh)[kq];
        v.x = fmaxf(fmaf(v.x, sc4.x, sh4.x), 0.f);
        v.y = fmaxf(fmaf(v.y, sc4.y, sh4.y), 0.f);
        v.z = fmaxf(fmaf(v.z, sc4.z, sh4.z), 0.f);
        v.w = fmaxf(fmaf(v.w, sc4.w, sh4.w), 0.f);
        reinterpret_cast<float4*>(Xl + r * 128)[kq] = v;
    }
#pragma unroll
    for (int i = 0; i < 8; i++) {
        int idx = t + i * 256;
        int k = idx >> 4;
        int cq = idx & 15;   // 64 padded cols; only 10 float4 groups valid (40 cols)
        float4 v = make_float4(0.f, 0.f, 0.f, 0.f);
        if (cq < 10) v = reinterpret_cast<const float4*>(W + k * 40)[cq];
        reinterpret_cast<float4*>(Wl + k * 64)[cq] = v;
    }
    __syncthreads();

    int tx = t & 15, ty = t >> 4;
    int rb = ty * 4, cb = tx * 4;
    float acc[4][4] = {};
    for (int k = 0; k < 128; k += 4) {
        float4 xv[4], wv[4];
#pragma unroll
        for (int i = 0; i < 4; i++)
            xv[i] = *reinterpret_cast<const float4*>(Xl + (rb + i) * 128 + k);
#pragma unroll
        for (int j = 0; j < 4; j++)
            wv[j] = *reinterpret_cast<const float4*>(Wl + (k + j) * 64 + cb);
#pragma unroll
        for (int i = 0; i < 4; i++) {
            acc[i][0] += xv[i].x * wv[0].x + xv[i].y * wv[1].x + xv[i].z * wv[2].x + xv[i].w * wv[3].x;
            acc[i][1] += xv[i].x * wv[0].y + xv[i].y * wv[1].y + xv[i].z * wv[2].y + xv[i].w * wv[3].y;
            acc[i][2] += xv[i].x * wv[0].z + xv[i].y * wv[1].z + xv[i].z * wv[2].z + xv[i].w * wv[3].z;
            acc[i][3] += xv[i].x * wv[0].w + xv[i].y * wv[1].w + xv[i].z * wv[2].w + xv[i].w * wv[3].w;
        }
    }
    if (tx < 10) {
#pragma unroll
        for (int i = 0; i < 4; i++) {
            int gr = row0 + rb + i;
            if (gr < n) {
                ushort4 o;
                o.x = f2bf(acc[i][0]);
                o.y = f2bf(acc[i][1]);
                o.z = f2bf(acc[i][2]);
                o.w = f2bf(acc[i][3]);
                *reinterpret_cast<ushort4*>(Y + (size_t)gr * 40 + cb) = o;
            }
        }
    }
}

// ---------------- CSR gather 128 bf16 (self-loop fused) + fused BN stats ----------------
// 32 nodes/block, wave w handles nodes [nb+8w, nb+8w+8).
// Index batching: all 64 lanes coalesce-load up to 64 csr indices + dinv, then
// broadcast via shfl -> the per-edge row loads are independent (deep MLP).
__global__ __launch_bounds__(256) void k_gather128s(const u32* __restrict__ xwb,
                                                    float* __restrict__ agg,
                                                    const int* __restrict__ rowstart,
                                                    const int* __restrict__ csr,
                                                    const float* __restrict__ dinv,
                                                    float* __restrict__ stats) {
    __shared__ float red[1024];  // [0..511]: sum per (wave,feat); [512..1023]: sum2
    int t = threadIdx.x;
    int w = t >> 6, l = t & 63;
    int nb = blockIdx.x * 32 + w * 8;
    float sx = 0.f, sy = 0.f, sxx = 0.f, syy = 0.f;
    for (int i = 0; i < 8; i++) {
        int node = nb + i;
        if (node >= NN) break;
        float dd = dinv[node];
        u32 us = xwb[(size_t)node * 64 + l];
        float ax = dd * dd * bf_lo(us);
        float ay = dd * dd * bf_hi(us);
        int p = rowstart[node], pe = rowstart[node + 1];
        while (p < pe) {
            int cnt = pe - p;
            if (cnt > 64) cnt = 64;
            int myidx = 0;
            float mydv = 0.f;
            if (l < cnt) {
                myidx = csr[p + l];        // coalesced
                mydv  = dd * dinv[myidx];  // random 4B, but batched
            }
            int j = 0;
            for (; j + 4 <= cnt; j += 4) {
                int s0 = __shfl(myidx, j);
                int s1 = __shfl(myidx, j + 1);
                int s2 = __shfl(myidx, j + 2);
                int s3 = __shfl(myidx, j + 3);
                float c0 = __shfl(mydv, j);
                float c1 = __shfl(mydv, j + 1);
                float c2 = __shfl(mydv, j + 2);
                float c3 = __shfl(mydv, j + 3);
                u32 u0 = xwb[(size_t)s0 * 64 + l];
                u32 u1 = xwb[(size_t)s1 * 64 + l];
                u32 u2 = xwb[(size_t)s2 * 64 + l];
                u32 u3 = xwb[(size_t)s3 * 64 + l];
                ax += c0 * bf_lo(u0) + c1 * bf_lo(u1) + c2 * bf_lo(u2) + c3 * bf_lo(u3);
                ay += c0 * bf_hi(u0) + c1 * bf_hi(u1) + c2 * bf_hi(u2) + c3 * bf_hi(u3);
            }
            for (; j < cnt; j++) {
                int s = __shfl(myidx, j);
                float c = __shfl(mydv, j);
                u32 u = xwb[(size_t)s * 64 + l];
                ax += c * bf_lo(u);
                ay += c * bf_hi(u);
            }
            p += cnt;
        }
        reinterpret_cast<float2*>(agg + (size_t)node * 128)[l] = make_float2(ax, ay);
        sx += ax; sxx += ax * ax;
        sy += ay; syy += ay * ay;
    }
    red[w * 128 + 2 * l]     = sx;
    red[w * 128 + 2 * l + 1] = sy;
    red[512 + w * 128 + 2 * l]     = sxx;
    red[512 + w * 128 + 2 * l + 1] = syy;
    __syncthreads();
    if (t < 128) {
        float s  = red[t] + red[128 + t] + red[256 + t] + red[384 + t];
        float s2 = red[512 + t] + red[640 + t] + red[768 + t] + red[896 + t];
        atomicAdd(&stats[t], s);
        atomicAdd(&stats[128 + t], s2);
    }
}

// ---------------- CSR gather 40 (bf16) + bias + log_softmax (fused, shfl-batched) ----------------
__global__ __launch_bounds__(256) void k_gather40_lsm(const u16* __restrict__ xwb,
                                                      const float* __restrict__ b2,
                                                      float* __restrict__ out,
                                                      const int* __restrict__ rowstart,
                                                      const int* __restrict__ csr,
                                                      const float* __restrict__ dinv) {
    int node = blockIdx.x * 4 + (threadIdx.x >> 6);
    if (node >= NN) return;
    int lane = threadIdx.x & 63;
    float dd = dinv[node];
    float acc = 0.f;
    if (lane < 40) acc = dd * dd * __uint_as_float((u32)xwb[(size_t)node * 40 + lane] << 16);
    int p = rowstart[node], pe = rowstart[node + 1];
    while (p < pe) {
        int cnt = pe - p;
        if (cnt > 64) cnt = 64;
        int myidx = 0;
        float mydv = 0.f;
        if (lane < cnt) {
            myidx = csr[p + lane];
            mydv  = dd * dinv[myidx];
        }
        int j = 0;
        for (; j + 2 <= cnt; j += 2) {
            int sA = __shfl(myidx, j);
            int sB = __shfl(myidx, j + 1);
            float cA = __shfl(mydv, j);
            float cB = __shfl(mydv, j + 1);
            float vA = 0.f, vB = 0.f;
            if (lane < 40) {
                vA = __uint_as_float((u32)xwb[(size_t)sA * 40 + lane] << 16);
                vB = __uint_as_float((u32)xwb[(size_t)sB * 40 + lane] << 16);
            }
            acc += cA * vA + cB * vB;
        }
        if (j < cnt) {
            int s = __shfl(myidx, j);
            float c = __shfl(mydv, j);
            if (lane < 40) acc += c * __uint_as_float((u32)xwb[(size_t)s * 40 + lane] << 16);
        }
        p += cnt;
    }
    float v = (lane < 40) ? acc + b2[lane] : -1e30f;
    float m = v;
#pragma unroll
    for (int o = 32; o; o >>= 1) m = fmaxf(m, __shfl_xor(m, o));
    float ex = (lane < 40) ? expf(v - m) : 0.f;
    float sum = ex;
#pragma unroll
    for (int o = 32; o; o >>= 1) sum += __shfl_xor(sum, o);
    if (lane < 40) out[(size_t)node * 40 + lane] = v - m - logf(sum);
}

// ---------------- launcher ----------------
extern "C" void kernel_launch(void* const* d_in, const int* in_sizes, int n_in,
                              void* d_out, int out_size, void* d_ws, size_t ws_size,
                              hipStream_t stream) {
    const float* x  = (const float*)d_in[0];
    const int* ei   = (const int*)d_in[1];
    const int* src  = ei;
    const int* dst  = ei + NE;
    const float* W0 = (const float*)d_in[2];
    const float* g0 = (const float*)d_in[4];
    const float* be0= (const float*)d_in[5];
    const float* W1 = (const float*)d_in[6];
    const float* g1 = (const float*)d_in[8];
    const float* be1= (const float*)d_in[9];
    const float* W2 = (const float*)d_in[10];
    const float* b2 = (const float*)d_in[11];
    float* out = (float*)d_out;

    // workspace layout (4-byte words), total 22,600,856 words = 90.4 MB
    float* ws      = (float*)d_ws;
    float* dinv    = ws;
    float* stats   = ws + 100000;
    int* rowstart  = (int*)(ws + 100256);
    int* gcnt      = (int*)(ws + 200260);
    int* gcur      = (int*)(ws + 200456);
    int* bktbase   = (int*)(ws + 200652);
    u32* bkt       = (u32*)(ws + 200856);
    int* csr       = (int*)(ws + 1800856);
    u16* bufA16    = (u16*)(ws + 3400856);
    float* bufB    = ws + 9800856;

    // ---- CSR build (bucketized, three-pass) ----
    k_zero_ints<<<2, 256, 0, stream>>>(gcnt, 392);  // gcnt + gcur contiguous
    k_bcount<<<(NE + CHA - 1) / CHA, 256, 0, stream>>>(dst, gcnt);
    k_scanbkt<<<1, 64, 0, stream>>>(gcnt, bktbase);
    k_bscatter<<<(NE + CHA - 1) / CHA, 256, 0, stream>>>(src, dst, bktbase, gcur, bkt);
    k_csr<<<NB, BKN, 0, stream>>>(bkt, bktbase, rowstart, csr, dinv);

    dim3 gg((NN + 63) / 64, 2);
    int gs = (NN + 31) / 32;   // gather blocks (32 nodes each) = 3125

    // ---- layer 0 ----
    k_gemm128<<<gg, 256, 0, stream>>>(x, W0, bufA16, NN, nullptr, nullptr, nullptr);
    k_zero_stats<<<1, 256, 0, stream>>>(stats);
    k_gather128s<<<gs, 256, 0, stream>>>((const u32*)bufA16, bufB, rowstart, csr, dinv, stats);

    // ---- layer 1 (BN0+ReLU fused into GEMM X-staging) ----
    k_gemm128<<<gg, 256, 0, stream>>>(bufB, W1, bufA16, NN, stats, g0, be0);
    k_zero_stats<<<1, 256, 0, stream>>>(stats);
    k_gather128s<<<gs, 256, 0, stream>>>((const u32*)bufA16, bufB, rowstart, csr, dinv, stats);

    // ---- layer 2 (BN1+ReLU fused into GEMM; gather + bias + log_softmax fused) ----
    k_gemm40p<<<(NN + 63) / 64, 256, 0, stream>>>(bufB, W2, bufA16, NN, stats, g1, be1);
    k_gather40_lsm<<<(NN + 3) / 4, 256, 0, stream>>>(bufA16, b2, out, rowstart, csr, dinv);
}